// Round 2
// baseline (8053.687 us; speedup 1.0000x reference)
//
#include <hip/hip_runtime.h>
#include <cmath>

__device__ __forceinline__ float sigm(float x) { return 1.0f / (1.0f + expf(-x)); }

// ---------------- edge scatter: agg[dst] += ea * h[src] ----------------
__global__ __launch_bounds__(256)
void scatter5(const float* __restrict__ h, const float* __restrict__ ea,
              const int* __restrict__ src, const int* __restrict__ dst,
              float* __restrict__ agg, int nE)
{
    int stride = gridDim.x * blockDim.x;
    for (int e = blockIdx.x * blockDim.x + threadIdx.x; e < nE; e += stride) {
        int s = src[e], d = dst[e];
        float w = ea[e];
        const float* hr = h + (size_t)s * 5;
        float* ar = agg + (size_t)d * 5;
        #pragma unroll
        for (int f = 0; f < 5; ++f) unsafeAtomicAdd(&ar[f], w * hr[f]);
    }
}

template<int D>
__global__ __launch_bounds__(256)
void scatterD(const float* __restrict__ h, const float* __restrict__ ea,
              const int* __restrict__ src, const int* __restrict__ dst,
              float* __restrict__ agg, int nE)
{
    constexpr int CH = D / 4;                 // 16 or 32
    constexpr int LOG = (CH == 32) ? 5 : 4;
    static_assert(CH == (1 << LOG), "CH must be pow2");
    int total = nE * CH;                       // <= 51.2M fits int
    int stride = gridDim.x * blockDim.x;
    for (int i = blockIdx.x * blockDim.x + threadIdx.x; i < total; i += stride) {
        int e = i >> LOG;
        int c = i & (CH - 1);
        int s = src[e], d = dst[e];
        float w = ea[e];
        const float4 v = *(const float4*)(h + (size_t)s * D + c * 4);
        float* a = agg + (size_t)d * D + c * 4;
        unsafeAtomicAdd(a + 0, w * v.x);
        unsafeAtomicAdd(a + 1, w * v.y);
        unsafeAtomicAdd(a + 2, w * v.z);
        unsafeAtomicAdd(a + 3, w * v.w);
    }
}

// -------- conv matmul: out = relu(h@ws + agg@wn + b), weights in LDS --------
// POOL: instead of storing rows, atomically accumulate into sums[bl[n]*DOUT].
template<int DIN, int DOUT, bool POOL>
__global__ __launch_bounds__(512)
void conv_mm(const float* __restrict__ h, const float* __restrict__ agg,
             const float* __restrict__ ws, const float* __restrict__ wn,
             const float* __restrict__ bias, float* __restrict__ out,
             const int* __restrict__ bl, float* __restrict__ sums, int nN)
{
    __shared__ __align__(16) float s_w[2 * DIN * DOUT];
    __shared__ __align__(16) float s_b[DOUT];
    for (int i = threadIdx.x; i < DIN * DOUT; i += 512) {
        s_w[i] = ws[i];
        s_w[DIN * DOUT + i] = wn[i];
    }
    for (int i = threadIdx.x; i < DOUT; i += 512) s_b[i] = bias[i];
    __syncthreads();

    constexpr int TPN = DOUT / 4;       // threads per node
    constexpr int HALF = 512 / TPN;     // nodes per half-pass
    constexpr int NPASS = HALF * 2;     // nodes per block pass (2 per thread)
    const int jj = (threadIdx.x % TPN) * 4;
    const int nsub = threadIdx.x / TPN;

    for (int base = blockIdx.x * NPASS; base < nN; base += gridDim.x * NPASS) {
        int n0 = base + nsub;
        int n1 = base + nsub + HALF;
        bool v0 = n0 < nN, v1 = n1 < nN;
        int n0c = v0 ? n0 : nN - 1;
        int n1c = v1 ? n1 : nN - 1;

        float acc0[4], acc1[4];
        #pragma unroll
        for (int q = 0; q < 4; ++q) { acc0[q] = s_b[jj + q]; acc1[q] = s_b[jj + q]; }

        const float* p0 = h + (size_t)n0c * DIN;
        const float* p1 = h + (size_t)n1c * DIN;
        const float* a0 = agg + (size_t)n0c * DIN;
        const float* a1 = agg + (size_t)n1c * DIN;

        if constexpr (DIN % 4 == 0) {
            for (int kc = 0; kc < DIN / 4; ++kc) {
                float4 x0 = *(const float4*)(p0 + kc * 4);
                float4 x1 = *(const float4*)(p1 + kc * 4);
                #pragma unroll
                for (int q = 0; q < 4; ++q) {
                    float xs0 = ((const float*)&x0)[q];
                    float xs1 = ((const float*)&x1)[q];
                    const float4 w4 = *(const float4*)(s_w + (size_t)(kc * 4 + q) * DOUT + jj);
                    acc0[0] += xs0 * w4.x; acc0[1] += xs0 * w4.y;
                    acc0[2] += xs0 * w4.z; acc0[3] += xs0 * w4.w;
                    acc1[0] += xs1 * w4.x; acc1[1] += xs1 * w4.y;
                    acc1[2] += xs1 * w4.z; acc1[3] += xs1 * w4.w;
                }
            }
            for (int kc = 0; kc < DIN / 4; ++kc) {
                float4 x0 = *(const float4*)(a0 + kc * 4);
                float4 x1 = *(const float4*)(a1 + kc * 4);
                #pragma unroll
                for (int q = 0; q < 4; ++q) {
                    float xs0 = ((const float*)&x0)[q];
                    float xs1 = ((const float*)&x1)[q];
                    const float4 w4 = *(const float4*)(s_w + (size_t)(DIN + kc * 4 + q) * DOUT + jj);
                    acc0[0] += xs0 * w4.x; acc0[1] += xs0 * w4.y;
                    acc0[2] += xs0 * w4.z; acc0[3] += xs0 * w4.w;
                    acc1[0] += xs1 * w4.x; acc1[1] += xs1 * w4.y;
                    acc1[2] += xs1 * w4.z; acc1[3] += xs1 * w4.w;
                }
            }
        } else {
            for (int k = 0; k < DIN; ++k) {
                float xs0 = p0[k], xs1 = p1[k];
                const float4 w4 = *(const float4*)(s_w + (size_t)k * DOUT + jj);
                acc0[0] += xs0 * w4.x; acc0[1] += xs0 * w4.y;
                acc0[2] += xs0 * w4.z; acc0[3] += xs0 * w4.w;
                acc1[0] += xs1 * w4.x; acc1[1] += xs1 * w4.y;
                acc1[2] += xs1 * w4.z; acc1[3] += xs1 * w4.w;
            }
            for (int k = 0; k < DIN; ++k) {
                float xs0 = a0[k], xs1 = a1[k];
                const float4 w4 = *(const float4*)(s_w + (size_t)(DIN + k) * DOUT + jj);
                acc0[0] += xs0 * w4.x; acc0[1] += xs0 * w4.y;
                acc0[2] += xs0 * w4.z; acc0[3] += xs0 * w4.w;
                acc1[0] += xs1 * w4.x; acc1[1] += xs1 * w4.y;
                acc1[2] += xs1 * w4.z; acc1[3] += xs1 * w4.w;
            }
        }
        if constexpr (POOL) {
            if (v0) {
                float* s = sums + (size_t)bl[n0] * DOUT + jj;
                #pragma unroll
                for (int q = 0; q < 4; ++q) unsafeAtomicAdd(s + q, fmaxf(acc0[q], 0.f));
            }
            if (v1) {
                float* s = sums + (size_t)bl[n1] * DOUT + jj;
                #pragma unroll
                for (int q = 0; q < 4; ++q) unsafeAtomicAdd(s + q, fmaxf(acc1[q], 0.f));
            }
        } else {
            if (v0) {
                float4 o;
                o.x = fmaxf(acc0[0], 0.f); o.y = fmaxf(acc0[1], 0.f);
                o.z = fmaxf(acc0[2], 0.f); o.w = fmaxf(acc0[3], 0.f);
                *(float4*)(out + (size_t)n0 * DOUT + jj) = o;
            }
            if (v1) {
                float4 o;
                o.x = fmaxf(acc1[0], 0.f); o.y = fmaxf(acc1[1], 0.f);
                o.z = fmaxf(acc1[2], 0.f); o.w = fmaxf(acc1[3], 0.f);
                *(float4*)(out + (size_t)n1 * DOUT + jj) = o;
            }
        }
    }
}

// ---------------- per-graph node counts ----------------
__global__ __launch_bounds__(256)
void cnt_kernel(const int* __restrict__ bl, float* __restrict__ cnt, int nN)
{
    int i = blockIdx.x * blockDim.x + threadIdx.x;
    if (i < nN) unsafeAtomicAdd(&cnt[bl[i]], 1.0f);
}

// ---------------- GRU (2 layers) + decoder, one block per sequence ----------------
__global__ __launch_bounds__(384)
void gru_kernel(const float* __restrict__ sums, const float* __restrict__ cnt,
                const int* __restrict__ lmap,
                const float* __restrict__ wih0, const float* __restrict__ whh0,
                const float* __restrict__ bih0, const float* __restrict__ bhh0,
                const float* __restrict__ wih1, const float* __restrict__ whh1,
                const float* __restrict__ bih1, const float* __restrict__ bhh1,
                const float* __restrict__ wdec, const float* __restrict__ bdec,
                float* __restrict__ out, int nG)
{
    __shared__ __align__(16) float s_x[16][128];   // layer input seq; overwritten with layer output
    __shared__ __align__(16) float s_xp[16][384];  // x projections
    __shared__ __align__(16) float s_h[128];
    __shared__ __align__(16) float s_gh[384];

    const int b = blockIdx.x;
    const int tid = threadIdx.x;

    // load seq = pooled[label_map[b, t]]
    for (int i = tid; i < 16 * 128; i += 384) {
        int t = i >> 7, j = i & 127;
        int g = lmap[b * 16 + t];
        s_x[t][j] = sums[(size_t)g * 128 + j] / fmaxf(cnt[g], 1.0f);
    }
    __syncthreads();

    for (int layer = 0; layer < 2; ++layer) {
        const float* wih = layer ? wih1 : wih0;
        const float* whh = layer ? whh1 : whh0;
        const float* bih = layer ? bih1 : bih0;
        const float* bhh = layer ? bhh1 : bhh0;

        // x_proj[t][g] = dot(x[t,:], wih[g,:]) + bih[g]
        {
            const int g = tid;
            float acc[16];
            #pragma unroll
            for (int t = 0; t < 16; ++t) acc[t] = 0.f;
            for (int kc = 0; kc < 32; ++kc) {
                float4 w = *(const float4*)(wih + (size_t)g * 128 + kc * 4);
                #pragma unroll
                for (int t = 0; t < 16; ++t) {
                    float4 xv = *(const float4*)&s_x[t][kc * 4];
                    acc[t] += w.x * xv.x + w.y * xv.y + w.z * xv.z + w.w * xv.w;
                }
            }
            float bg = bih[g];
            #pragma unroll
            for (int t = 0; t < 16; ++t) s_xp[t][g] = acc[t] + bg;
        }
        __syncthreads();
        if (tid < 128) s_h[tid] = 0.f;
        __syncthreads();

        for (int t = 0; t < 16; ++t) {
            // gh[g] = dot(whh[g,:], h) + bhh[g]
            {
                const int g = tid;
                float acc = bhh[g];
                for (int kc = 0; kc < 32; ++kc) {
                    float4 w = *(const float4*)(whh + (size_t)g * 128 + kc * 4);
                    float4 hv = *(const float4*)&s_h[kc * 4];
                    acc += w.x * hv.x + w.y * hv.y + w.z * hv.z + w.w * hv.w;
                }
                s_gh[g] = acc;
            }
            __syncthreads();
            if (tid < 128) {
                int j = tid;
                float r = sigm(s_xp[t][j] + s_gh[j]);
                float z = sigm(s_xp[t][128 + j] + s_gh[128 + j]);
                float n = tanhf(s_xp[t][256 + j] + r * s_gh[256 + j]);
                float hn = (1.f - z) * n + z * s_h[j];
                s_h[j] = hn;
                s_x[t][j] = hn;    // layer output o_l[t]
            }
            __syncthreads();
        }
    }

    // decoder: predictions[b,t] = sigmoid(o2[t]·wdec + bdec); final == predictions[b,15]
    if (tid < 16) {
        float acc = bdec[0];
        const float* o = &s_x[tid][0];
        for (int j = 0; j < 128; ++j) acc += o[j] * wdec[j];
        float p = sigm(acc);
        out[b * 16 + tid] = p;
        if (tid == 15) out[nG + b] = p;
    }
}

extern "C" void kernel_launch(void* const* d_in, const int* in_sizes, int n_in,
                              void* d_out, int out_size, void* d_ws, size_t ws_size,
                              hipStream_t stream)
{
    const float* x    = (const float*)d_in[0];
    const float* ea   = (const float*)d_in[1];
    const int*   ei   = (const int*)d_in[2];
    const int*   bl   = (const int*)d_in[3];
    const int*   lmap = (const int*)d_in[4];
    const float* ws0 = (const float*)d_in[5];
    const float* wn0 = (const float*)d_in[6];
    const float* b0  = (const float*)d_in[7];
    const float* ws1 = (const float*)d_in[8];
    const float* wn1 = (const float*)d_in[9];
    const float* b1  = (const float*)d_in[10];
    const float* ws2 = (const float*)d_in[11];
    const float* wn2 = (const float*)d_in[12];
    const float* b2  = (const float*)d_in[13];
    const float* wih0 = (const float*)d_in[14];
    const float* whh0 = (const float*)d_in[15];
    const float* bih0 = (const float*)d_in[16];
    const float* bhh0 = (const float*)d_in[17];
    const float* wih1 = (const float*)d_in[18];
    const float* whh1 = (const float*)d_in[19];
    const float* bih1 = (const float*)d_in[20];
    const float* bhh1 = (const float*)d_in[21];
    const float* wdec = (const float*)d_in[22];
    const float* bdec = (const float*)d_in[23];
    float* out = (float*)d_out;

    const int nN = in_sizes[0] / 5;     // 200000
    const int nE = in_sizes[1];         // 1600000
    const int nG = in_sizes[4];         // 4096
    const int B  = nG / 16;             // 256

    const int* src = ei;
    const int* dst = ei + nE;

    // Workspace layout (~207 MB total):
    //   R0: nN*64   (h1; later low half of agg128)
    //   R1: nN*64   (agg5 / agg64; later high half of agg128)
    //   R2: nN*128  (h2)
    //   sums: nG*128, cnt: nG
    float* R0   = (float*)d_ws;
    float* R1   = R0 + (size_t)nN * 64;
    float* R2   = R1 + (size_t)nN * 64;
    float* sums = R2 + (size_t)nN * 128;
    float* cnt  = sums + (size_t)nG * 128;
    float* agg128 = R0;   // R0+R1 contiguous = nN*128

    // ---- layer 0: agg x (5 feats) into R1; h1 = conv(x, agg) -> R0 ----
    hipMemsetAsync(R1, 0, (size_t)nN * 5 * sizeof(float), stream);
    scatter5<<<3125, 256, 0, stream>>>(x, ea, src, dst, R1, nE);
    conv_mm<5, 64, false><<<512, 512, 0, stream>>>(x, R1, ws0, wn0, b0, R0, nullptr, nullptr, nN);

    // ---- layer 1: agg h1 (64) into R1; h2 = conv(h1, agg) -> R2 ----
    hipMemsetAsync(R1, 0, (size_t)nN * 64 * sizeof(float), stream);
    scatterD<64><<<8192, 256, 0, stream>>>(R0, ea, src, dst, R1, nE);
    conv_mm<64, 128, false><<<512, 512, 0, stream>>>(R0, R1, ws1, wn1, b1, R2, nullptr, nullptr, nN);

    // ---- layer 2: agg h2 (128) into R0∪R1; conv with fused mean-pool sums ----
    hipMemsetAsync(agg128, 0, (size_t)nN * 128 * sizeof(float), stream);
    scatterD<128><<<8192, 256, 0, stream>>>(R2, ea, src, dst, agg128, nE);
    hipMemsetAsync(sums, 0, ((size_t)nG * 128 + nG) * sizeof(float), stream);
    cnt_kernel<<<(nN + 255) / 256, 256, 0, stream>>>(bl, cnt, nN);
    conv_mm<128, 128, true><<<512, 512, 0, stream>>>(R2, agg128, ws2, wn2, b2, nullptr, bl, sums, nN);

    // ---- GRU x2 + decoder ----
    gru_kernel<<<B, 384, 0, stream>>>(sums, cnt, lmap,
                                      wih0, whh0, bih0, bhh0,
                                      wih1, whh1, bih1, bhh1,
                                      wdec, bdec, out, nG);
}

// Round 3
// 3678.284 us; speedup vs baseline: 2.1895x; 2.1895x over previous
//
#include <hip/hip_runtime.h>
#include <cmath>

__device__ __forceinline__ float sigm(float x) { return 1.0f / (1.0f + expf(-x)); }

// ================= CSR build =================
__global__ __launch_bounds__(256)
void hist_kernel(const int* __restrict__ dst, int* __restrict__ deg, int nE)
{
    int i = blockIdx.x * blockDim.x + threadIdx.x;
    if (i < nE) atomicAdd(&deg[dst[i]], 1);
}

// exclusive scan; each block handles 1024 elements (4/thread), optional block sums
__global__ __launch_bounds__(256)
void scan_blocks(const int* __restrict__ in, int* __restrict__ out,
                 int* __restrict__ bsum, int n)
{
    __shared__ int sh[256];
    int base = blockIdx.x * 1024;
    int t = threadIdx.x;
    int v[4];
    int s = 0;
    #pragma unroll
    for (int q = 0; q < 4; ++q) {
        int idx = base + t * 4 + q;
        v[q] = (idx < n) ? in[idx] : 0;
        s += v[q];
    }
    sh[t] = s;
    __syncthreads();
    for (int off = 1; off < 256; off <<= 1) {
        int x = (t >= off) ? sh[t - off] : 0;
        __syncthreads();
        sh[t] += x;
        __syncthreads();
    }
    int run = (t == 0) ? 0 : sh[t - 1];
    #pragma unroll
    for (int q = 0; q < 4; ++q) {
        int idx = base + t * 4 + q;
        if (idx < n) out[idx] = run;
        run += v[q];
    }
    if (t == 255 && bsum) bsum[blockIdx.x] = sh[255];
}

__global__ __launch_bounds__(256)
void scan_add(int* __restrict__ out, const int* __restrict__ boff, int n)
{
    int i = blockIdx.x * blockDim.x + threadIdx.x;
    if (i < n) out[i] += boff[i >> 10];
}

// pack (src, w) into one int: src<<14 | round(w*16383)
__global__ __launch_bounds__(256)
void fill_kernel(const int* __restrict__ src, const int* __restrict__ dst,
                 const float* __restrict__ ea, int* __restrict__ cursor,
                 int* __restrict__ csr, int nE)
{
    int i = blockIdx.x * blockDim.x + threadIdx.x;
    if (i < nE) {
        int d = dst[i];
        int p = atomicAdd(&cursor[d], 1);
        int wq = __float2int_rn(ea[i] * 16383.f);
        csr[p] = (src[i] << 14) | wq;
    }
}

// ================= aggregation (gather) =================
__global__ __launch_bounds__(256)
void agg5_kernel(const float* __restrict__ x, const int* __restrict__ rowptr,
                 const int* __restrict__ csr, float* __restrict__ agg, int nN, int nE)
{
    int n = blockIdx.x * blockDim.x + threadIdx.x;
    if (n >= nN) return;
    int e0 = rowptr[n];
    int e1 = (n + 1 < nN) ? rowptr[n + 1] : nE;
    float a[5] = {0.f, 0.f, 0.f, 0.f, 0.f};
    for (int e = e0; e < e1; ++e) {
        int v = csr[e];
        int s = ((unsigned)v) >> 14;
        float w = (float)(v & 16383) * (1.f / 16383.f);
        const float* xr = x + (size_t)s * 5;
        #pragma unroll
        for (int f = 0; f < 5; ++f) a[f] += w * xr[f];
    }
    float* ar = agg + (size_t)n * 5;
    #pragma unroll
    for (int f = 0; f < 5; ++f) ar[f] = a[f];
}

template<int D>
__global__ __launch_bounds__(256)
void aggD_kernel(const float* __restrict__ h, const int* __restrict__ rowptr,
                 const int* __restrict__ csr, float* __restrict__ agg, int nN, int nE)
{
    constexpr int TPN = D / 4;              // 16 or 32 threads per node
    int gid = blockIdx.x * blockDim.x + threadIdx.x;
    int c = gid & (TPN - 1);
    int n = gid / TPN;
    if (n >= nN) return;
    int e0 = rowptr[n];
    int e1 = (n + 1 < nN) ? rowptr[n + 1] : nE;
    float4 acc = {0.f, 0.f, 0.f, 0.f};
    for (int e = e0; e < e1; ++e) {
        int v = csr[e];
        int s = ((unsigned)v) >> 14;
        float w = (float)(v & 16383) * (1.f / 16383.f);
        const float4 hv = *(const float4*)(h + (size_t)s * D + c * 4);
        acc.x += w * hv.x; acc.y += w * hv.y;
        acc.z += w * hv.z; acc.w += w * hv.w;
    }
    *(float4*)(agg + (size_t)n * D + c * 4) = acc;
}

// -------- conv matmul: out = relu(h@ws + agg@wn + b), weights in LDS --------
// POOL: instead of storing rows, atomically accumulate into sums[bl[n]*DOUT].
template<int DIN, int DOUT, bool POOL>
__global__ __launch_bounds__(512)
void conv_mm(const float* __restrict__ h, const float* __restrict__ agg,
             const float* __restrict__ ws, const float* __restrict__ wn,
             const float* __restrict__ bias, float* __restrict__ out,
             const int* __restrict__ bl, float* __restrict__ sums, int nN)
{
    __shared__ __align__(16) float s_w[2 * DIN * DOUT];
    __shared__ __align__(16) float s_b[DOUT];
    for (int i = threadIdx.x; i < DIN * DOUT; i += 512) {
        s_w[i] = ws[i];
        s_w[DIN * DOUT + i] = wn[i];
    }
    for (int i = threadIdx.x; i < DOUT; i += 512) s_b[i] = bias[i];
    __syncthreads();

    constexpr int TPN = DOUT / 4;       // threads per node
    constexpr int HALF = 512 / TPN;     // nodes per half-pass
    constexpr int NPASS = HALF * 2;     // nodes per block pass (2 per thread)
    const int jj = (threadIdx.x % TPN) * 4;
    const int nsub = threadIdx.x / TPN;

    for (int base = blockIdx.x * NPASS; base < nN; base += gridDim.x * NPASS) {
        int n0 = base + nsub;
        int n1 = base + nsub + HALF;
        bool v0 = n0 < nN, v1 = n1 < nN;
        int n0c = v0 ? n0 : nN - 1;
        int n1c = v1 ? n1 : nN - 1;

        float acc0[4], acc1[4];
        #pragma unroll
        for (int q = 0; q < 4; ++q) { acc0[q] = s_b[jj + q]; acc1[q] = s_b[jj + q]; }

        const float* p0 = h + (size_t)n0c * DIN;
        const float* p1 = h + (size_t)n1c * DIN;
        const float* a0 = agg + (size_t)n0c * DIN;
        const float* a1 = agg + (size_t)n1c * DIN;

        if constexpr (DIN % 4 == 0) {
            for (int kc = 0; kc < DIN / 4; ++kc) {
                float4 x0 = *(const float4*)(p0 + kc * 4);
                float4 x1 = *(const float4*)(p1 + kc * 4);
                #pragma unroll
                for (int q = 0; q < 4; ++q) {
                    float xs0 = ((const float*)&x0)[q];
                    float xs1 = ((const float*)&x1)[q];
                    const float4 w4 = *(const float4*)(s_w + (size_t)(kc * 4 + q) * DOUT + jj);
                    acc0[0] += xs0 * w4.x; acc0[1] += xs0 * w4.y;
                    acc0[2] += xs0 * w4.z; acc0[3] += xs0 * w4.w;
                    acc1[0] += xs1 * w4.x; acc1[1] += xs1 * w4.y;
                    acc1[2] += xs1 * w4.z; acc1[3] += xs1 * w4.w;
                }
            }
            for (int kc = 0; kc < DIN / 4; ++kc) {
                float4 x0 = *(const float4*)(a0 + kc * 4);
                float4 x1 = *(const float4*)(a1 + kc * 4);
                #pragma unroll
                for (int q = 0; q < 4; ++q) {
                    float xs0 = ((const float*)&x0)[q];
                    float xs1 = ((const float*)&x1)[q];
                    const float4 w4 = *(const float4*)(s_w + (size_t)(DIN + kc * 4 + q) * DOUT + jj);
                    acc0[0] += xs0 * w4.x; acc0[1] += xs0 * w4.y;
                    acc0[2] += xs0 * w4.z; acc0[3] += xs0 * w4.w;
                    acc1[0] += xs1 * w4.x; acc1[1] += xs1 * w4.y;
                    acc1[2] += xs1 * w4.z; acc1[3] += xs1 * w4.w;
                }
            }
        } else {
            for (int k = 0; k < DIN; ++k) {
                float xs0 = p0[k], xs1 = p1[k];
                const float4 w4 = *(const float4*)(s_w + (size_t)k * DOUT + jj);
                acc0[0] += xs0 * w4.x; acc0[1] += xs0 * w4.y;
                acc0[2] += xs0 * w4.z; acc0[3] += xs0 * w4.w;
                acc1[0] += xs1 * w4.x; acc1[1] += xs1 * w4.y;
                acc1[2] += xs1 * w4.z; acc1[3] += xs1 * w4.w;
            }
            for (int k = 0; k < DIN; ++k) {
                float xs0 = a0[k], xs1 = a1[k];
                const float4 w4 = *(const float4*)(s_w + (size_t)(DIN + k) * DOUT + jj);
                acc0[0] += xs0 * w4.x; acc0[1] += xs0 * w4.y;
                acc0[2] += xs0 * w4.z; acc0[3] += xs0 * w4.w;
                acc1[0] += xs1 * w4.x; acc1[1] += xs1 * w4.y;
                acc1[2] += xs1 * w4.z; acc1[3] += xs1 * w4.w;
            }
        }
        if constexpr (POOL) {
            if (v0) {
                float* s = sums + (size_t)bl[n0] * DOUT + jj;
                #pragma unroll
                for (int q = 0; q < 4; ++q) unsafeAtomicAdd(s + q, fmaxf(acc0[q], 0.f));
            }
            if (v1) {
                float* s = sums + (size_t)bl[n1] * DOUT + jj;
                #pragma unroll
                for (int q = 0; q < 4; ++q) unsafeAtomicAdd(s + q, fmaxf(acc1[q], 0.f));
            }
        } else {
            if (v0) {
                float4 o;
                o.x = fmaxf(acc0[0], 0.f); o.y = fmaxf(acc0[1], 0.f);
                o.z = fmaxf(acc0[2], 0.f); o.w = fmaxf(acc0[3], 0.f);
                *(float4*)(out + (size_t)n0 * DOUT + jj) = o;
            }
            if (v1) {
                float4 o;
                o.x = fmaxf(acc1[0], 0.f); o.y = fmaxf(acc1[1], 0.f);
                o.z = fmaxf(acc1[2], 0.f); o.w = fmaxf(acc1[3], 0.f);
                *(float4*)(out + (size_t)n1 * DOUT + jj) = o;
            }
        }
    }
}

// ---------------- per-graph node counts ----------------
__global__ __launch_bounds__(256)
void cnt_kernel(const int* __restrict__ bl, float* __restrict__ cnt, int nN)
{
    int i = blockIdx.x * blockDim.x + threadIdx.x;
    if (i < nN) unsafeAtomicAdd(&cnt[bl[i]], 1.0f);
}

// ---------------- GRU (2 layers) + decoder, one block per sequence ----------------
__global__ __launch_bounds__(384)
void gru_kernel(const float* __restrict__ sums, const float* __restrict__ cnt,
                const int* __restrict__ lmap,
                const float* __restrict__ wih0, const float* __restrict__ whh0,
                const float* __restrict__ bih0, const float* __restrict__ bhh0,
                const float* __restrict__ wih1, const float* __restrict__ whh1,
                const float* __restrict__ bih1, const float* __restrict__ bhh1,
                const float* __restrict__ wdec, const float* __restrict__ bdec,
                float* __restrict__ out, int nG)
{
    __shared__ __align__(16) float s_x[16][128];   // layer input seq; overwritten with layer output
    __shared__ __align__(16) float s_xp[16][384];  // x projections
    __shared__ __align__(16) float s_h[128];
    __shared__ __align__(16) float s_gh[384];

    const int b = blockIdx.x;
    const int tid = threadIdx.x;

    // load seq = pooled[label_map[b, t]]
    for (int i = tid; i < 16 * 128; i += 384) {
        int t = i >> 7, j = i & 127;
        int g = lmap[b * 16 + t];
        s_x[t][j] = sums[(size_t)g * 128 + j] / fmaxf(cnt[g], 1.0f);
    }
    __syncthreads();

    for (int layer = 0; layer < 2; ++layer) {
        const float* wih = layer ? wih1 : wih0;
        const float* whh = layer ? whh1 : whh0;
        const float* bih = layer ? bih1 : bih0;
        const float* bhh = layer ? bhh1 : bhh0;

        // x_proj[t][g] = dot(x[t,:], wih[g,:]) + bih[g]
        {
            const int g = tid;
            float acc[16];
            #pragma unroll
            for (int t = 0; t < 16; ++t) acc[t] = 0.f;
            for (int kc = 0; kc < 32; ++kc) {
                float4 w = *(const float4*)(wih + (size_t)g * 128 + kc * 4);
                #pragma unroll
                for (int t = 0; t < 16; ++t) {
                    float4 xv = *(const float4*)&s_x[t][kc * 4];
                    acc[t] += w.x * xv.x + w.y * xv.y + w.z * xv.z + w.w * xv.w;
                }
            }
            float bg = bih[g];
            #pragma unroll
            for (int t = 0; t < 16; ++t) s_xp[t][g] = acc[t] + bg;
        }
        __syncthreads();
        if (tid < 128) s_h[tid] = 0.f;
        __syncthreads();

        for (int t = 0; t < 16; ++t) {
            // gh[g] = dot(whh[g,:], h) + bhh[g]
            {
                const int g = tid;
                float acc = bhh[g];
                for (int kc = 0; kc < 32; ++kc) {
                    float4 w = *(const float4*)(whh + (size_t)g * 128 + kc * 4);
                    float4 hv = *(const float4*)&s_h[kc * 4];
                    acc += w.x * hv.x + w.y * hv.y + w.z * hv.z + w.w * hv.w;
                }
                s_gh[g] = acc;
            }
            __syncthreads();
            if (tid < 128) {
                int j = tid;
                float r = sigm(s_xp[t][j] + s_gh[j]);
                float z = sigm(s_xp[t][128 + j] + s_gh[128 + j]);
                float n = tanhf(s_xp[t][256 + j] + r * s_gh[256 + j]);
                float hn = (1.f - z) * n + z * s_h[j];
                s_h[j] = hn;
                s_x[t][j] = hn;    // layer output o_l[t]
            }
            __syncthreads();
        }
    }

    // decoder: predictions[b,t] = sigmoid(o2[t]·wdec + bdec); final == predictions[b,15]
    if (tid < 16) {
        float acc = bdec[0];
        const float* o = &s_x[tid][0];
        for (int j = 0; j < 128; ++j) acc += o[j] * wdec[j];
        float p = sigm(acc);
        out[b * 16 + tid] = p;
        if (tid == 15) out[nG + b] = p;
    }
}

extern "C" void kernel_launch(void* const* d_in, const int* in_sizes, int n_in,
                              void* d_out, int out_size, void* d_ws, size_t ws_size,
                              hipStream_t stream)
{
    const float* x    = (const float*)d_in[0];
    const float* ea   = (const float*)d_in[1];
    const int*   ei   = (const int*)d_in[2];
    const int*   bl   = (const int*)d_in[3];
    const int*   lmap = (const int*)d_in[4];
    const float* ws0 = (const float*)d_in[5];
    const float* wn0 = (const float*)d_in[6];
    const float* b0  = (const float*)d_in[7];
    const float* ws1 = (const float*)d_in[8];
    const float* wn1 = (const float*)d_in[9];
    const float* b1  = (const float*)d_in[10];
    const float* ws2 = (const float*)d_in[11];
    const float* wn2 = (const float*)d_in[12];
    const float* b2  = (const float*)d_in[13];
    const float* wih0 = (const float*)d_in[14];
    const float* whh0 = (const float*)d_in[15];
    const float* bih0 = (const float*)d_in[16];
    const float* bhh0 = (const float*)d_in[17];
    const float* wih1 = (const float*)d_in[18];
    const float* whh1 = (const float*)d_in[19];
    const float* bih1 = (const float*)d_in[20];
    const float* bhh1 = (const float*)d_in[21];
    const float* wdec = (const float*)d_in[22];
    const float* bdec = (const float*)d_in[23];
    float* out = (float*)d_out;

    const int nN = in_sizes[0] / 5;     // 200000
    const int nE = in_sizes[1];         // 1600000
    const int nG = in_sizes[4];         // 4096
    const int B  = nG / 16;             // 256

    const int* src = ei;
    const int* dst = ei + nE;

    // Workspace layout (~205 MiB):
    //   R0: nN*64 (h1; later low half of agg128)
    //   R1: nN*64 (agg5/agg64; later high half of agg128)
    //   R2: nN*128 (h2)
    //   sums nG*128, cnt nG, deg/cursor nN, rowptr nN, bsum 256, boff 256, csr nE
    float* R0   = (float*)d_ws;
    float* R1   = R0 + (size_t)nN * 64;
    float* R2   = R1 + (size_t)nN * 64;
    float* sums = R2 + (size_t)nN * 128;
    float* cnt  = sums + (size_t)nG * 128;
    int* deg    = (int*)(cnt + nG);
    int* rowptr = deg + nN;
    int* bsum   = rowptr + nN;
    int* boff   = bsum + 256;
    int* csr    = boff + 256;
    float* agg128 = R0;   // R0+R1 contiguous = nN*128

    const int nblocks_scan = (nN + 1023) / 1024;   // 196

    // ---- build CSR (dst-sorted edges), reused by all 3 layers ----
    hipMemsetAsync(deg, 0, (size_t)nN * sizeof(int), stream);
    hist_kernel<<<(nE + 255) / 256, 256, 0, stream>>>(dst, deg, nE);
    scan_blocks<<<nblocks_scan, 256, 0, stream>>>(deg, rowptr, bsum, nN);
    scan_blocks<<<1, 256, 0, stream>>>(bsum, boff, nullptr, nblocks_scan);
    scan_add<<<(nN + 255) / 256, 256, 0, stream>>>(rowptr, boff, nN);
    hipMemcpyAsync(deg, rowptr, (size_t)nN * sizeof(int), hipMemcpyDeviceToDevice, stream);
    fill_kernel<<<(nE + 255) / 256, 256, 0, stream>>>(src, dst, ea, deg, csr, nE);

    // ---- layer 0: agg x (5 feats) into R1; h1 = conv(x, agg) -> R0 ----
    agg5_kernel<<<(nN + 255) / 256, 256, 0, stream>>>(x, rowptr, csr, R1, nN, nE);
    conv_mm<5, 64, false><<<512, 512, 0, stream>>>(x, R1, ws0, wn0, b0, R0, nullptr, nullptr, nN);

    // ---- layer 1: agg h1 (64) into R1; h2 = conv(h1, agg) -> R2 ----
    aggD_kernel<64><<<(nN * 16 + 255) / 256, 256, 0, stream>>>(R0, rowptr, csr, R1, nN, nE);
    conv_mm<64, 128, false><<<512, 512, 0, stream>>>(R0, R1, ws1, wn1, b1, R2, nullptr, nullptr, nN);

    // ---- layer 2: agg h2 (128) into R0∪R1; conv with fused mean-pool sums ----
    aggD_kernel<128><<<(nN * 32 + 255) / 256, 256, 0, stream>>>(R2, rowptr, csr, agg128, nN, nE);
    hipMemsetAsync(sums, 0, ((size_t)nG * 128 + nG) * sizeof(float), stream);
    cnt_kernel<<<(nN + 255) / 256, 256, 0, stream>>>(bl, cnt, nN);
    conv_mm<128, 128, true><<<512, 512, 0, stream>>>(R2, agg128, ws2, wn2, b2, nullptr, bl, sums, nN);

    // ---- GRU x2 + decoder ----
    gru_kernel<<<B, 384, 0, stream>>>(sums, cnt, lmap,
                                      wih0, whh0, bih0, bhh0,
                                      wih1, whh1, bih1, bhh1,
                                      wdec, bdec, out, nG);
}

// Round 4
// 1624.323 us; speedup vs baseline: 4.9582x; 2.2645x over previous
//
#include <hip/hip_runtime.h>
#include <cmath>

__device__ __forceinline__ float sigm(float x) { return 1.0f / (1.0f + expf(-x)); }

// ================= CSR build =================
__global__ __launch_bounds__(256)
void hist_kernel(const int* __restrict__ dst, int* __restrict__ deg, int nE)
{
    int i = blockIdx.x * blockDim.x + threadIdx.x;
    if (i < nE) atomicAdd(&deg[dst[i]], 1);
}

__global__ __launch_bounds__(256)
void scan_blocks(const int* __restrict__ in, int* __restrict__ out,
                 int* __restrict__ bsum, int n)
{
    __shared__ int sh[256];
    int base = blockIdx.x * 1024;
    int t = threadIdx.x;
    int v[4];
    int s = 0;
    #pragma unroll
    for (int q = 0; q < 4; ++q) {
        int idx = base + t * 4 + q;
        v[q] = (idx < n) ? in[idx] : 0;
        s += v[q];
    }
    sh[t] = s;
    __syncthreads();
    for (int off = 1; off < 256; off <<= 1) {
        int x = (t >= off) ? sh[t - off] : 0;
        __syncthreads();
        sh[t] += x;
        __syncthreads();
    }
    int run = (t == 0) ? 0 : sh[t - 1];
    #pragma unroll
    for (int q = 0; q < 4; ++q) {
        int idx = base + t * 4 + q;
        if (idx < n) out[idx] = run;
        run += v[q];
    }
    if (t == 255 && bsum) bsum[blockIdx.x] = sh[255];
}

__global__ __launch_bounds__(256)
void scan_add(int* __restrict__ out, const int* __restrict__ boff, int n)
{
    int i = blockIdx.x * blockDim.x + threadIdx.x;
    if (i < n) out[i] += boff[i >> 10];
}

// pack (src, w) into one int: src<<14 | round(w*16383)
__global__ __launch_bounds__(256)
void fill_kernel(const int* __restrict__ src, const int* __restrict__ dst,
                 const float* __restrict__ ea, int* __restrict__ cursor,
                 int* __restrict__ csr, int nE)
{
    int i = blockIdx.x * blockDim.x + threadIdx.x;
    if (i < nE) {
        int d = dst[i];
        int p = atomicAdd(&cursor[d], 1);
        int wq = __float2int_rn(ea[i] * 16383.f);
        csr[p] = (src[i] << 14) | wq;
    }
}

// ================= aggregation (gather) =================
__global__ __launch_bounds__(256)
void agg5_kernel(const float* __restrict__ x, const int* __restrict__ rowptr,
                 const int* __restrict__ csr, float* __restrict__ agg, int nN, int nE)
{
    int n = blockIdx.x * blockDim.x + threadIdx.x;
    if (n >= nN) return;
    int e0 = rowptr[n];
    int e1 = (n + 1 < nN) ? rowptr[n + 1] : nE;
    float a[5] = {0.f, 0.f, 0.f, 0.f, 0.f};
    for (int e = e0; e < e1; ++e) {
        int v = csr[e];
        int s = ((unsigned)v) >> 14;
        float w = (float)(v & 16383) * (1.f / 16383.f);
        const float* xr = x + (size_t)s * 5;
        #pragma unroll
        for (int f = 0; f < 5; ++f) a[f] += w * xr[f];
    }
    float* ar = agg + (size_t)n * 5;
    #pragma unroll
    for (int f = 0; f < 5; ++f) ar[f] = a[f];
}

template<int D>
__global__ __launch_bounds__(256)
void aggD_kernel(const float* __restrict__ h, const int* __restrict__ rowptr,
                 const int* __restrict__ csr, float* __restrict__ agg, int nN, int nE)
{
    constexpr int TPN = D / 4;
    int gid = blockIdx.x * blockDim.x + threadIdx.x;
    int c = gid & (TPN - 1);
    int n = gid / TPN;
    if (n >= nN) return;
    int e0 = rowptr[n];
    int e1 = (n + 1 < nN) ? rowptr[n + 1] : nE;
    float4 acc = {0.f, 0.f, 0.f, 0.f};
    for (int e = e0; e < e1; ++e) {
        int v = csr[e];
        int s = ((unsigned)v) >> 14;
        float w = (float)(v & 16383) * (1.f / 16383.f);
        const float4 hv = *(const float4*)(h + (size_t)s * D + c * 4);
        acc.x += w * hv.x; acc.y += w * hv.y;
        acc.z += w * hv.z; acc.w += w * hv.w;
    }
    *(float4*)(agg + (size_t)n * D + c * 4) = acc;
}

// -------- small conv (layer 0): out = relu(h@ws + agg@wn + b) --------
template<int DIN, int DOUT>
__global__ __launch_bounds__(512)
void conv_mm(const float* __restrict__ h, const float* __restrict__ agg,
             const float* __restrict__ ws, const float* __restrict__ wn,
             const float* __restrict__ bias, float* __restrict__ out, int nN)
{
    __shared__ __align__(16) float s_w[2 * DIN * DOUT];
    __shared__ __align__(16) float s_b[DOUT];
    for (int i = threadIdx.x; i < DIN * DOUT; i += 512) {
        s_w[i] = ws[i];
        s_w[DIN * DOUT + i] = wn[i];
    }
    for (int i = threadIdx.x; i < DOUT; i += 512) s_b[i] = bias[i];
    __syncthreads();

    constexpr int TPN = DOUT / 4;
    constexpr int HALF = 512 / TPN;
    constexpr int NPASS = HALF * 2;
    const int jj = (threadIdx.x % TPN) * 4;
    const int nsub = threadIdx.x / TPN;

    for (int base = blockIdx.x * NPASS; base < nN; base += gridDim.x * NPASS) {
        int n0 = base + nsub;
        int n1 = base + nsub + HALF;
        bool v0 = n0 < nN, v1 = n1 < nN;
        int n0c = v0 ? n0 : nN - 1;
        int n1c = v1 ? n1 : nN - 1;

        float acc0[4], acc1[4];
        #pragma unroll
        for (int q = 0; q < 4; ++q) { acc0[q] = s_b[jj + q]; acc1[q] = s_b[jj + q]; }

        const float* p0 = h + (size_t)n0c * DIN;
        const float* p1 = h + (size_t)n1c * DIN;
        const float* a0 = agg + (size_t)n0c * DIN;
        const float* a1 = agg + (size_t)n1c * DIN;

        for (int k = 0; k < DIN; ++k) {
            float xs0 = p0[k], xs1 = p1[k];
            const float4 w4 = *(const float4*)(s_w + (size_t)k * DOUT + jj);
            acc0[0] += xs0 * w4.x; acc0[1] += xs0 * w4.y;
            acc0[2] += xs0 * w4.z; acc0[3] += xs0 * w4.w;
            acc1[0] += xs1 * w4.x; acc1[1] += xs1 * w4.y;
            acc1[2] += xs1 * w4.z; acc1[3] += xs1 * w4.w;
        }
        for (int k = 0; k < DIN; ++k) {
            float xs0 = a0[k], xs1 = a1[k];
            const float4 w4 = *(const float4*)(s_w + (size_t)(DIN + k) * DOUT + jj);
            acc0[0] += xs0 * w4.x; acc0[1] += xs0 * w4.y;
            acc0[2] += xs0 * w4.z; acc0[3] += xs0 * w4.w;
            acc1[0] += xs1 * w4.x; acc1[1] += xs1 * w4.y;
            acc1[2] += xs1 * w4.z; acc1[3] += xs1 * w4.w;
        }
        if (v0) {
            float4 o;
            o.x = fmaxf(acc0[0], 0.f); o.y = fmaxf(acc0[1], 0.f);
            o.z = fmaxf(acc0[2], 0.f); o.w = fmaxf(acc0[3], 0.f);
            *(float4*)(out + (size_t)n0 * DOUT + jj) = o;
        }
        if (v1) {
            float4 o;
            o.x = fmaxf(acc1[0], 0.f); o.y = fmaxf(acc1[1], 0.f);
            o.z = fmaxf(acc1[2], 0.f); o.w = fmaxf(acc1[3], 0.f);
            *(float4*)(out + (size_t)n1 * DOUT + jj) = o;
        }
    }
}

// -------- big conv as tiled GEMM: out = relu(h@ws + agg@wn + b) --------
// DOUT=128 fixed. 64-node tile staged in LDS per 32-k panel; weights paneled.
// POOL: atomically accumulate relu'd rows into sums[bl[n]] instead of storing.
template<int DIN, bool POOL>
__global__ __launch_bounds__(256)
void conv_gemm(const float* __restrict__ h, const float* __restrict__ agg,
               const float* __restrict__ ws, const float* __restrict__ wn,
               const float* __restrict__ bias, float* __restrict__ out,
               const int* __restrict__ bl, float* __restrict__ sums, int nN)
{
    constexpr int DOUT = 128, TN = 64, KT = 32;
    constexpr int NP = DIN / KT;              // k-panels per matrix
    __shared__ __align__(16) float s_in[TN][KT + 1];   // +1 pad: bank-spread
    __shared__ __align__(16) float s_wp[KT][DOUT];

    const int tid = threadIdx.x;
    const int jb = tid & 15;          // col block: cols jb*8 .. jb*8+7
    const int nr = tid >> 4;          // node sub: nodes nr + 16*{0..3}
    const int tile0 = blockIdx.x * TN;  // nN == gridDim.x * TN exactly

    float acc[4][8];
    #pragma unroll
    for (int j = 0; j < 8; ++j) {
        float b = bias[jb * 8 + j];
        #pragma unroll
        for (int n = 0; n < 4; ++n) acc[n][j] = b;
    }

    #pragma unroll
    for (int m = 0; m < 2; ++m) {
        const float* M = m ? agg : h;
        const float* W = m ? wn : ws;
        for (int kp = 0; kp < NP; ++kp) {
            // stage input tile slab: 64 nodes x 32 k  (512 float4)
            #pragma unroll
            for (int r = 0; r < 2; ++r) {
                int f = tid + r * 256;
                int row = f >> 3, c4 = (f & 7) * 4;
                float4 v = *(const float4*)(M + (size_t)(tile0 + row) * DIN + kp * KT + c4);
                s_in[row][c4 + 0] = v.x; s_in[row][c4 + 1] = v.y;
                s_in[row][c4 + 2] = v.z; s_in[row][c4 + 3] = v.w;
            }
            // stage weight panel: 32 k x 128  (1024 float4)
            #pragma unroll
            for (int r = 0; r < 4; ++r) {
                int f = tid + r * 256;
                int row = f >> 5, c4 = (f & 31) * 4;
                *(float4*)(&s_wp[row][c4]) =
                    *(const float4*)(W + (size_t)(kp * KT + row) * DOUT + c4);
            }
            __syncthreads();
            #pragma unroll 4
            for (int k = 0; k < KT; ++k) {
                float4 w0 = *(const float4*)(&s_wp[k][jb * 8]);
                float4 w1 = *(const float4*)(&s_wp[k][jb * 8 + 4]);
                #pragma unroll
                for (int n = 0; n < 4; ++n) {
                    float xv = s_in[nr + n * 16][k];
                    acc[n][0] += xv * w0.x; acc[n][1] += xv * w0.y;
                    acc[n][2] += xv * w0.z; acc[n][3] += xv * w0.w;
                    acc[n][4] += xv * w1.x; acc[n][5] += xv * w1.y;
                    acc[n][6] += xv * w1.z; acc[n][7] += xv * w1.w;
                }
            }
            __syncthreads();
        }
    }

    if constexpr (POOL) {
        #pragma unroll
        for (int n = 0; n < 4; ++n) {
            int node = tile0 + nr + n * 16;
            int g = bl[node];
            float* s = sums + (size_t)g * 128 + jb * 8;
            #pragma unroll
            for (int j = 0; j < 8; ++j) unsafeAtomicAdd(s + j, fmaxf(acc[n][j], 0.f));
        }
    } else {
        #pragma unroll
        for (int n = 0; n < 4; ++n) {
            int node = tile0 + nr + n * 16;
            float4 o0, o1;
            o0.x = fmaxf(acc[n][0], 0.f); o0.y = fmaxf(acc[n][1], 0.f);
            o0.z = fmaxf(acc[n][2], 0.f); o0.w = fmaxf(acc[n][3], 0.f);
            o1.x = fmaxf(acc[n][4], 0.f); o1.y = fmaxf(acc[n][5], 0.f);
            o1.z = fmaxf(acc[n][6], 0.f); o1.w = fmaxf(acc[n][7], 0.f);
            *(float4*)(out + (size_t)node * 128 + jb * 8) = o0;
            *(float4*)(out + (size_t)node * 128 + jb * 8 + 4) = o1;
        }
    }
}

// ---------------- per-graph node counts ----------------
__global__ __launch_bounds__(256)
void cnt_kernel(const int* __restrict__ bl, float* __restrict__ cnt, int nN)
{
    int i = blockIdx.x * blockDim.x + threadIdx.x;
    if (i < nN) unsafeAtomicAdd(&cnt[bl[i]], 1.0f);
}

// ---------------- GRU (2 layers) + decoder, one block per sequence ----------------
__global__ __launch_bounds__(384)
void gru_kernel(const float* __restrict__ sums, const float* __restrict__ cnt,
                const int* __restrict__ lmap,
                const float* __restrict__ wih0, const float* __restrict__ whh0,
                const float* __restrict__ bih0, const float* __restrict__ bhh0,
                const float* __restrict__ wih1, const float* __restrict__ whh1,
                const float* __restrict__ bih1, const float* __restrict__ bhh1,
                const float* __restrict__ wdec, const float* __restrict__ bdec,
                float* __restrict__ out, int nG)
{
    __shared__ __align__(16) float s_x[16][128];
    __shared__ __align__(16) float s_xp[16][384];
    __shared__ __align__(16) float s_h[128];
    __shared__ __align__(16) float s_gh[384];

    const int b = blockIdx.x;
    const int tid = threadIdx.x;

    for (int i = tid; i < 16 * 128; i += 384) {
        int t = i >> 7, j = i & 127;
        int g = lmap[b * 16 + t];
        s_x[t][j] = sums[(size_t)g * 128 + j] / fmaxf(cnt[g], 1.0f);
    }
    __syncthreads();

    for (int layer = 0; layer < 2; ++layer) {
        const float* wih = layer ? wih1 : wih0;
        const float* whh = layer ? whh1 : whh0;
        const float* bih = layer ? bih1 : bih0;
        const float* bhh = layer ? bhh1 : bhh0;

        {
            const int g = tid;
            float acc[16];
            #pragma unroll
            for (int t = 0; t < 16; ++t) acc[t] = 0.f;
            for (int kc = 0; kc < 32; ++kc) {
                float4 w = *(const float4*)(wih + (size_t)g * 128 + kc * 4);
                #pragma unroll
                for (int t = 0; t < 16; ++t) {
                    float4 xv = *(const float4*)&s_x[t][kc * 4];
                    acc[t] += w.x * xv.x + w.y * xv.y + w.z * xv.z + w.w * xv.w;
                }
            }
            float bg = bih[g];
            #pragma unroll
            for (int t = 0; t < 16; ++t) s_xp[t][g] = acc[t] + bg;
        }
        __syncthreads();
        if (tid < 128) s_h[tid] = 0.f;
        __syncthreads();

        for (int t = 0; t < 16; ++t) {
            {
                const int g = tid;
                float acc = bhh[g];
                for (int kc = 0; kc < 32; ++kc) {
                    float4 w = *(const float4*)(whh + (size_t)g * 128 + kc * 4);
                    float4 hv = *(const float4*)&s_h[kc * 4];
                    acc += w.x * hv.x + w.y * hv.y + w.z * hv.z + w.w * hv.w;
                }
                s_gh[g] = acc;
            }
            __syncthreads();
            if (tid < 128) {
                int j = tid;
                float r = sigm(s_xp[t][j] + s_gh[j]);
                float z = sigm(s_xp[t][128 + j] + s_gh[128 + j]);
                float n = tanhf(s_xp[t][256 + j] + r * s_gh[256 + j]);
                float hn = (1.f - z) * n + z * s_h[j];
                s_h[j] = hn;
                s_x[t][j] = hn;
            }
            __syncthreads();
        }
    }

    if (tid < 16) {
        float acc = bdec[0];
        const float* o = &s_x[tid][0];
        for (int j = 0; j < 128; ++j) acc += o[j] * wdec[j];
        float p = sigm(acc);
        out[b * 16 + tid] = p;
        if (tid == 15) out[nG + b] = p;
    }
}

extern "C" void kernel_launch(void* const* d_in, const int* in_sizes, int n_in,
                              void* d_out, int out_size, void* d_ws, size_t ws_size,
                              hipStream_t stream)
{
    const float* x    = (const float*)d_in[0];
    const float* ea   = (const float*)d_in[1];
    const int*   ei   = (const int*)d_in[2];
    const int*   bl   = (const int*)d_in[3];
    const int*   lmap = (const int*)d_in[4];
    const float* ws0 = (const float*)d_in[5];
    const float* wn0 = (const float*)d_in[6];
    const float* b0  = (const float*)d_in[7];
    const float* ws1 = (const float*)d_in[8];
    const float* wn1 = (const float*)d_in[9];
    const float* b1  = (const float*)d_in[10];
    const float* ws2 = (const float*)d_in[11];
    const float* wn2 = (const float*)d_in[12];
    const float* b2  = (const float*)d_in[13];
    const float* wih0 = (const float*)d_in[14];
    const float* whh0 = (const float*)d_in[15];
    const float* bih0 = (const float*)d_in[16];
    const float* bhh0 = (const float*)d_in[17];
    const float* wih1 = (const float*)d_in[18];
    const float* whh1 = (const float*)d_in[19];
    const float* bih1 = (const float*)d_in[20];
    const float* bhh1 = (const float*)d_in[21];
    const float* wdec = (const float*)d_in[22];
    const float* bdec = (const float*)d_in[23];
    float* out = (float*)d_out;

    const int nN = in_sizes[0] / 5;     // 200000
    const int nE = in_sizes[1];         // 1600000
    const int nG = in_sizes[4];         // 4096
    const int B  = nG / 16;             // 256

    const int* src = ei;
    const int* dst = ei + nE;

    float* R0   = (float*)d_ws;
    float* R1   = R0 + (size_t)nN * 64;
    float* R2   = R1 + (size_t)nN * 64;
    float* sums = R2 + (size_t)nN * 128;
    float* cnt  = sums + (size_t)nG * 128;
    int* deg    = (int*)(cnt + nG);
    int* rowptr = deg + nN;
    int* bsum   = rowptr + nN;
    int* boff   = bsum + 256;
    int* csr    = boff + 256;
    float* agg128 = R0;

    const int nblocks_scan = (nN + 1023) / 1024;

    // ---- build CSR (dst-sorted edges), reused by all 3 layers ----
    hipMemsetAsync(deg, 0, (size_t)nN * sizeof(int), stream);
    hist_kernel<<<(nE + 255) / 256, 256, 0, stream>>>(dst, deg, nE);
    scan_blocks<<<nblocks_scan, 256, 0, stream>>>(deg, rowptr, bsum, nN);
    scan_blocks<<<1, 256, 0, stream>>>(bsum, boff, nullptr, nblocks_scan);
    scan_add<<<(nN + 255) / 256, 256, 0, stream>>>(rowptr, boff, nN);
    hipMemcpyAsync(deg, rowptr, (size_t)nN * sizeof(int), hipMemcpyDeviceToDevice, stream);
    fill_kernel<<<(nE + 255) / 256, 256, 0, stream>>>(src, dst, ea, deg, csr, nE);

    // ---- layer 0: agg x (5) into R1; h1 = conv(x, agg) -> R0 ----
    agg5_kernel<<<(nN + 255) / 256, 256, 0, stream>>>(x, rowptr, csr, R1, nN, nE);
    conv_mm<5, 64><<<512, 512, 0, stream>>>(x, R1, ws0, wn0, b0, R0, nN);

    // ---- layer 1: agg h1 (64) into R1; h2 = conv_gemm -> R2 ----
    aggD_kernel<64><<<(nN * 16 + 255) / 256, 256, 0, stream>>>(R0, rowptr, csr, R1, nN, nE);
    conv_gemm<64, false><<<nN / 64, 256, 0, stream>>>(R0, R1, ws1, wn1, b1, R2, nullptr, nullptr, nN);

    // ---- layer 2: agg h2 (128) into R0∪R1; conv_gemm with fused mean-pool ----
    aggD_kernel<128><<<(nN * 32 + 255) / 256, 256, 0, stream>>>(R2, rowptr, csr, agg128, nN, nE);
    hipMemsetAsync(sums, 0, ((size_t)nG * 128 + nG) * sizeof(float), stream);
    cnt_kernel<<<(nN + 255) / 256, 256, 0, stream>>>(bl, cnt, nN);
    conv_gemm<128, true><<<nN / 64, 256, 0, stream>>>(R2, agg128, ws2, wn2, b2, nullptr, bl, sums, nN);

    // ---- GRU x2 + decoder ----
    gru_kernel<<<B, 384, 0, stream>>>(sums, cnt, lmap,
                                      wih0, whh0, bih0, bhh0,
                                      wih1, whh1, bih1, bhh1,
                                      wdec, bdec, out, nG);
}

// Round 5
// 912.912 us; speedup vs baseline: 8.8220x; 1.7793x over previous
//
#include <hip/hip_runtime.h>
#include <cmath>

typedef __attribute__((ext_vector_type(8))) short short8b;
typedef __attribute__((ext_vector_type(4))) float floatx4;

__device__ __forceinline__ float sigm(float x) { return 1.0f / (1.0f + expf(-x)); }

// round-to-nearest-even f32 -> bf16 bits
__device__ __forceinline__ unsigned short f2bf(float f) {
    unsigned u = __float_as_uint(f);
    unsigned r = (u + 0x7FFFu + ((u >> 16) & 1u)) >> 16;
    return (unsigned short)r;
}

// ================= CSR build =================
__global__ __launch_bounds__(256)
void hist_kernel(const int* __restrict__ dst, int* __restrict__ deg, int nE)
{
    int i = blockIdx.x * blockDim.x + threadIdx.x;
    if (i < nE) atomicAdd(&deg[dst[i]], 1);
}

__global__ __launch_bounds__(256)
void scan_blocks(const int* __restrict__ in, int* __restrict__ out,
                 int* __restrict__ bsum, int n)
{
    __shared__ int sh[256];
    int base = blockIdx.x * 1024;
    int t = threadIdx.x;
    int v[4];
    int s = 0;
    #pragma unroll
    for (int q = 0; q < 4; ++q) {
        int idx = base + t * 4 + q;
        v[q] = (idx < n) ? in[idx] : 0;
        s += v[q];
    }
    sh[t] = s;
    __syncthreads();
    for (int off = 1; off < 256; off <<= 1) {
        int x = (t >= off) ? sh[t - off] : 0;
        __syncthreads();
        sh[t] += x;
        __syncthreads();
    }
    int run = (t == 0) ? 0 : sh[t - 1];
    #pragma unroll
    for (int q = 0; q < 4; ++q) {
        int idx = base + t * 4 + q;
        if (idx < n) out[idx] = run;
        run += v[q];
    }
    if (t == 255 && bsum) bsum[blockIdx.x] = sh[255];
}

__global__ __launch_bounds__(256)
void scan_add(int* __restrict__ out, const int* __restrict__ boff, int n)
{
    int i = blockIdx.x * blockDim.x + threadIdx.x;
    if (i < n) out[i] += boff[i >> 10];
}

// pack (src, w) into one int: src<<14 | round(w*16383)
__global__ __launch_bounds__(256)
void fill_kernel(const int* __restrict__ src, const int* __restrict__ dst,
                 const float* __restrict__ ea, int* __restrict__ cursor,
                 int* __restrict__ csr, int nE)
{
    int i = blockIdx.x * blockDim.x + threadIdx.x;
    if (i < nE) {
        int d = dst[i];
        int p = atomicAdd(&cursor[d], 1);
        int wq = __float2int_rn(ea[i] * 16383.f);
        csr[p] = (src[i] << 14) | wq;
    }
}

// ================= aggregation (gather) =================
__global__ __launch_bounds__(256)
void agg5_kernel(const float* __restrict__ x, const int* __restrict__ rowptr,
                 const int* __restrict__ csr, float* __restrict__ agg, int nN, int nE)
{
    int n = blockIdx.x * blockDim.x + threadIdx.x;
    if (n >= nN) return;
    int e0 = rowptr[n];
    int e1 = (n + 1 < nN) ? rowptr[n + 1] : nE;
    float a[5] = {0.f, 0.f, 0.f, 0.f, 0.f};
    for (int e = e0; e < e1; ++e) {
        int v = csr[e];
        int s = ((unsigned)v) >> 14;
        float w = (float)(v & 16383) * (1.f / 16383.f);
        const float* xr = x + (size_t)s * 5;
        #pragma unroll
        for (int f = 0; f < 5; ++f) a[f] += w * xr[f];
    }
    float* ar = agg + (size_t)n * 5;
    #pragma unroll
    for (int f = 0; f < 5; ++f) ar[f] = a[f];
}

template<int D>
__global__ __launch_bounds__(256)
void aggD_kernel(const float* __restrict__ h, const int* __restrict__ rowptr,
                 const int* __restrict__ csr, float* __restrict__ agg, int nN, int nE)
{
    constexpr int TPN = D / 4;
    int gid = blockIdx.x * blockDim.x + threadIdx.x;
    int c = gid & (TPN - 1);
    int n = gid / TPN;
    if (n >= nN) return;
    int e0 = rowptr[n];
    int e1 = (n + 1 < nN) ? rowptr[n + 1] : nE;
    float4 acc = {0.f, 0.f, 0.f, 0.f};
    for (int e = e0; e < e1; ++e) {
        int v = csr[e];
        int s = ((unsigned)v) >> 14;
        float w = (float)(v & 16383) * (1.f / 16383.f);
        const float4 hv = *(const float4*)(h + (size_t)s * D + c * 4);
        acc.x += w * hv.x; acc.y += w * hv.y;
        acc.z += w * hv.z; acc.w += w * hv.w;
    }
    *(float4*)(agg + (size_t)n * D + c * 4) = acc;
}

// -------- small conv (layer 0): out = relu(h@ws + agg@wn + b) --------
template<int DIN, int DOUT>
__global__ __launch_bounds__(512)
void conv_mm(const float* __restrict__ h, const float* __restrict__ agg,
             const float* __restrict__ ws, const float* __restrict__ wn,
             const float* __restrict__ bias, float* __restrict__ out, int nN)
{
    __shared__ __align__(16) float s_w[2 * DIN * DOUT];
    __shared__ __align__(16) float s_b[DOUT];
    for (int i = threadIdx.x; i < DIN * DOUT; i += 512) {
        s_w[i] = ws[i];
        s_w[DIN * DOUT + i] = wn[i];
    }
    for (int i = threadIdx.x; i < DOUT; i += 512) s_b[i] = bias[i];
    __syncthreads();

    constexpr int TPN = DOUT / 4;
    constexpr int HALF = 512 / TPN;
    constexpr int NPASS = HALF * 2;
    const int jj = (threadIdx.x % TPN) * 4;
    const int nsub = threadIdx.x / TPN;

    for (int base = blockIdx.x * NPASS; base < nN; base += gridDim.x * NPASS) {
        int n0 = base + nsub;
        int n1 = base + nsub + HALF;
        bool v0 = n0 < nN, v1 = n1 < nN;
        int n0c = v0 ? n0 : nN - 1;
        int n1c = v1 ? n1 : nN - 1;

        float acc0[4], acc1[4];
        #pragma unroll
        for (int q = 0; q < 4; ++q) { acc0[q] = s_b[jj + q]; acc1[q] = s_b[jj + q]; }

        const float* p0 = h + (size_t)n0c * DIN;
        const float* p1 = h + (size_t)n1c * DIN;
        const float* a0 = agg + (size_t)n0c * DIN;
        const float* a1 = agg + (size_t)n1c * DIN;

        for (int k = 0; k < DIN; ++k) {
            float xs0 = p0[k], xs1 = p1[k];
            const float4 w4 = *(const float4*)(s_w + (size_t)k * DOUT + jj);
            acc0[0] += xs0 * w4.x; acc0[1] += xs0 * w4.y;
            acc0[2] += xs0 * w4.z; acc0[3] += xs0 * w4.w;
            acc1[0] += xs1 * w4.x; acc1[1] += xs1 * w4.y;
            acc1[2] += xs1 * w4.z; acc1[3] += xs1 * w4.w;
        }
        for (int k = 0; k < DIN; ++k) {
            float xs0 = a0[k], xs1 = a1[k];
            const float4 w4 = *(const float4*)(s_w + (size_t)(DIN + k) * DOUT + jj);
            acc0[0] += xs0 * w4.x; acc0[1] += xs0 * w4.y;
            acc0[2] += xs0 * w4.z; acc0[3] += xs0 * w4.w;
            acc1[0] += xs1 * w4.x; acc1[1] += xs1 * w4.y;
            acc1[2] += xs1 * w4.z; acc1[3] += xs1 * w4.w;
        }
        if (v0) {
            float4 o;
            o.x = fmaxf(acc0[0], 0.f); o.y = fmaxf(acc0[1], 0.f);
            o.z = fmaxf(acc0[2], 0.f); o.w = fmaxf(acc0[3], 0.f);
            *(float4*)(out + (size_t)n0 * DOUT + jj) = o;
        }
        if (v1) {
            float4 o;
            o.x = fmaxf(acc1[0], 0.f); o.y = fmaxf(acc1[1], 0.f);
            o.z = fmaxf(acc1[2], 0.f); o.w = fmaxf(acc1[3], 0.f);
            *(float4*)(out + (size_t)n1 * DOUT + jj) = o;
        }
    }
}

// -------- weight prep: Wt[col][k] bf16, k = [self(DIN) | nei(DIN)] --------
template<int DIN>
__global__ __launch_bounds__(256)
void prep_w(const float* __restrict__ ws, const float* __restrict__ wn,
            unsigned short* __restrict__ wt)
{
    constexpr int KC = 2 * DIN;
    int idx = blockIdx.x * 256 + threadIdx.x;
    if (idx >= 128 * KC) return;
    int col = idx / KC, k = idx % KC;
    float v = (k < DIN) ? ws[(size_t)k * 128 + col] : wn[(size_t)(k - DIN) * 128 + col];
    wt[(size_t)col * KC + k] = f2bf(v);
}

// -------- big conv via MFMA: out = relu([h|agg] @ [ws;wn] + b) --------
// block: 256 thr / 4 waves; 64-node tile; wave tile = 32 nodes x 64 cols.
template<int DIN, bool POOL>
__global__ __launch_bounds__(256)
void conv_mfma(const float* __restrict__ h, const float* __restrict__ agg,
               const unsigned short* __restrict__ wt,   // [128][2*DIN] bf16
               const float* __restrict__ bias, float* __restrict__ out,
               const int* __restrict__ bl, float* __restrict__ sums, int nN)
{
    constexpr int KC = 2 * DIN;
    constexpr int NPANEL = KC / 64;
    constexpr int LDK = 72;                       // padded row stride (ushorts), 144B (16B mult)
    __shared__ unsigned short sA[64 * LDK];
    __shared__ unsigned short sB[128 * LDK];

    const int tid  = threadIdx.x;
    const int lane = tid & 63;
    const int w    = tid >> 6;
    const int nb   = (w >> 1) * 32;   // wave node base (0 or 32)
    const int cb   = (w & 1) * 64;    // wave col base (0 or 64)
    const int r15  = lane & 15;
    const int k8   = (lane >> 4) * 8;
    const int tile0 = blockIdx.x * 64;            // nN % 64 == 0

    const floatx4 zero4 = {0.f, 0.f, 0.f, 0.f};
    floatx4 acc[2][4];
    #pragma unroll
    for (int m = 0; m < 2; ++m)
        #pragma unroll
        for (int n = 0; n < 4; ++n) acc[m][n] = zero4;

    for (int kp = 0; kp < NPANEL; ++kp) {
        const int kbase = kp * 64;
        const float* M = (kbase < DIN) ? h : agg;
        const int koff = (kbase < DIN) ? kbase : (kbase - DIN);
        // stage A: 64 nodes x 64 k (f32 -> bf16)
        #pragma unroll
        for (int r = 0; r < 4; ++r) {
            int f = tid + r * 256;
            int node = f >> 4, kq = f & 15;
            float4 v = *(const float4*)(M + (size_t)(tile0 + node) * DIN + koff + kq * 4);
            ushort4 o;
            o.x = f2bf(v.x); o.y = f2bf(v.y); o.z = f2bf(v.z); o.w = f2bf(v.w);
            *(ushort4*)(&sA[node * LDK + kq * 4]) = o;
        }
        // stage B: 128 cols x 64 k (already bf16)
        #pragma unroll
        for (int r = 0; r < 8; ++r) {
            int f = tid + r * 256;
            int col = f >> 4, kq = f & 15;
            *(ushort4*)(&sB[col * LDK + kq * 4]) =
                *(const ushort4*)(wt + (size_t)col * KC + kbase + kq * 4);
        }
        __syncthreads();
        #pragma unroll
        for (int ks = 0; ks < 2; ++ks) {
            const int kk = ks * 32 + k8;
            short8b a0 = *(const short8b*)(&sA[(nb + r15) * LDK + kk]);
            short8b a1 = *(const short8b*)(&sA[(nb + 16 + r15) * LDK + kk]);
            #pragma unroll
            for (int n = 0; n < 4; ++n) {
                short8b b = *(const short8b*)(&sB[(cb + n * 16 + r15) * LDK + kk]);
                acc[0][n] = __builtin_amdgcn_mfma_f32_16x16x32_bf16(a0, b, acc[0][n], 0, 0, 0);
                acc[1][n] = __builtin_amdgcn_mfma_f32_16x16x32_bf16(a1, b, acc[1][n], 0, 0, 0);
            }
        }
        __syncthreads();
    }

    // epilogue: C/D layout col=lane&15, row=(lane>>4)*4+j
    const int row4 = (lane >> 4) * 4;
    int gi[2][4];
    if constexpr (POOL) {
        #pragma unroll
        for (int m = 0; m < 2; ++m)
            #pragma unroll
            for (int j = 0; j < 4; ++j)
                gi[m][j] = bl[tile0 + nb + m * 16 + row4 + j];
    }
    #pragma unroll
    for (int n = 0; n < 4; ++n) {
        const int col = cb + n * 16 + r15;
        const float bv = bias[col];
        #pragma unroll
        for (int m = 0; m < 2; ++m) {
            #pragma unroll
            for (int j = 0; j < 4; ++j) {
                float val = fmaxf(acc[m][n][j] + bv, 0.f);
                if constexpr (POOL) {
                    unsafeAtomicAdd(&sums[(size_t)gi[m][j] * 128 + col], val);
                } else {
                    int node = tile0 + nb + m * 16 + row4 + j;
                    out[(size_t)node * 128 + col] = val;
                }
            }
        }
    }
}

// ---------------- per-graph node counts ----------------
__global__ __launch_bounds__(256)
void cnt_kernel(const int* __restrict__ bl, float* __restrict__ cnt, int nN)
{
    int i = blockIdx.x * blockDim.x + threadIdx.x;
    if (i < nN) unsafeAtomicAdd(&cnt[bl[i]], 1.0f);
}

// ---------------- GRU (2 layers) + decoder, one block per sequence ----------------
__global__ __launch_bounds__(384)
void gru_kernel(const float* __restrict__ sums, const float* __restrict__ cnt,
                const int* __restrict__ lmap,
                const float* __restrict__ wih0, const float* __restrict__ whh0,
                const float* __restrict__ bih0, const float* __restrict__ bhh0,
                const float* __restrict__ wih1, const float* __restrict__ whh1,
                const float* __restrict__ bih1, const float* __restrict__ bhh1,
                const float* __restrict__ wdec, const float* __restrict__ bdec,
                float* __restrict__ out, int nG)
{
    __shared__ __align__(16) float s_x[16][128];
    __shared__ __align__(16) float s_xp[16][384];
    __shared__ __align__(16) float s_h[128];
    __shared__ __align__(16) float s_gh[384];

    const int b = blockIdx.x;
    const int tid = threadIdx.x;

    for (int i = tid; i < 16 * 128; i += 384) {
        int t = i >> 7, j = i & 127;
        int g = lmap[b * 16 + t];
        s_x[t][j] = sums[(size_t)g * 128 + j] / fmaxf(cnt[g], 1.0f);
    }
    __syncthreads();

    for (int layer = 0; layer < 2; ++layer) {
        const float* wih = layer ? wih1 : wih0;
        const float* whh = layer ? whh1 : whh0;
        const float* bih = layer ? bih1 : bih0;
        const float* bhh = layer ? bhh1 : bhh0;

        {
            const int g = tid;
            float acc[16];
            #pragma unroll
            for (int t = 0; t < 16; ++t) acc[t] = 0.f;
            for (int kc = 0; kc < 32; ++kc) {
                float4 w = *(const float4*)(wih + (size_t)g * 128 + kc * 4);
                #pragma unroll
                for (int t = 0; t < 16; ++t) {
                    float4 xv = *(const float4*)&s_x[t][kc * 4];
                    acc[t] += w.x * xv.x + w.y * xv.y + w.z * xv.z + w.w * xv.w;
                }
            }
            float bg = bih[g];
            #pragma unroll
            for (int t = 0; t < 16; ++t) s_xp[t][g] = acc[t] + bg;
        }
        __syncthreads();
        if (tid < 128) s_h[tid] = 0.f;
        __syncthreads();

        for (int t = 0; t < 16; ++t) {
            {
                const int g = tid;
                float acc = bhh[g];
                for (int kc = 0; kc < 32; ++kc) {
                    float4 w = *(const float4*)(whh + (size_t)g * 128 + kc * 4);
                    float4 hv = *(const float4*)&s_h[kc * 4];
                    acc += w.x * hv.x + w.y * hv.y + w.z * hv.z + w.w * hv.w;
                }
                s_gh[g] = acc;
            }
            __syncthreads();
            if (tid < 128) {
                int j = tid;
                float r = sigm(s_xp[t][j] + s_gh[j]);
                float z = sigm(s_xp[t][128 + j] + s_gh[128 + j]);
                float n = tanhf(s_xp[t][256 + j] + r * s_gh[256 + j]);
                float hn = (1.f - z) * n + z * s_h[j];
                s_h[j] = hn;
                s_x[t][j] = hn;
            }
            __syncthreads();
        }
    }

    if (tid < 16) {
        float acc = bdec[0];
        const float* o = &s_x[tid][0];
        for (int j = 0; j < 128; ++j) acc += o[j] * wdec[j];
        float p = sigm(acc);
        out[b * 16 + tid] = p;
        if (tid == 15) out[nG + b] = p;
    }
}

extern "C" void kernel_launch(void* const* d_in, const int* in_sizes, int n_in,
                              void* d_out, int out_size, void* d_ws, size_t ws_size,
                              hipStream_t stream)
{
    const float* x    = (const float*)d_in[0];
    const float* ea   = (const float*)d_in[1];
    const int*   ei   = (const int*)d_in[2];
    const int*   bl   = (const int*)d_in[3];
    const int*   lmap = (const int*)d_in[4];
    const float* ws0 = (const float*)d_in[5];
    const float* wn0 = (const float*)d_in[6];
    const float* b0  = (const float*)d_in[7];
    const float* ws1 = (const float*)d_in[8];
    const float* wn1 = (const float*)d_in[9];
    const float* b1  = (const float*)d_in[10];
    const float* ws2 = (const float*)d_in[11];
    const float* wn2 = (const float*)d_in[12];
    const float* b2  = (const float*)d_in[13];
    const float* wih0 = (const float*)d_in[14];
    const float* whh0 = (const float*)d_in[15];
    const float* bih0 = (const float*)d_in[16];
    const float* bhh0 = (const float*)d_in[17];
    const float* wih1 = (const float*)d_in[18];
    const float* whh1 = (const float*)d_in[19];
    const float* bih1 = (const float*)d_in[20];
    const float* bhh1 = (const float*)d_in[21];
    const float* wdec = (const float*)d_in[22];
    const float* bdec = (const float*)d_in[23];
    float* out = (float*)d_out;

    const int nN = in_sizes[0] / 5;     // 200000
    const int nE = in_sizes[1];         // 1600000
    const int nG = in_sizes[4];         // 4096
    const int B  = nG / 16;             // 256

    const int* src = ei;
    const int* dst = ei + nE;

    float* R0   = (float*)d_ws;
    float* R1   = R0 + (size_t)nN * 64;
    float* R2   = R1 + (size_t)nN * 64;
    float* sums = R2 + (size_t)nN * 128;
    float* cnt  = sums + (size_t)nG * 128;
    int* deg    = (int*)(cnt + nG);
    int* rowptr = deg + nN;
    int* bsum   = rowptr + nN;
    int* boff   = bsum + 256;
    int* csr    = boff + 256;
    unsigned short* wt1 = (unsigned short*)(csr + nE);   // [128][128] bf16
    unsigned short* wt2 = wt1 + 128 * 128;               // [128][256] bf16
    float* agg128 = R0;

    const int nblocks_scan = (nN + 1023) / 1024;

    // ---- build CSR (dst-sorted edges), reused by all 3 layers ----
    hipMemsetAsync(deg, 0, (size_t)nN * sizeof(int), stream);
    hist_kernel<<<(nE + 255) / 256, 256, 0, stream>>>(dst, deg, nE);
    scan_blocks<<<nblocks_scan, 256, 0, stream>>>(deg, rowptr, bsum, nN);
    scan_blocks<<<1, 256, 0, stream>>>(bsum, boff, nullptr, nblocks_scan);
    scan_add<<<(nN + 255) / 256, 256, 0, stream>>>(rowptr, boff, nN);
    hipMemcpyAsync(deg, rowptr, (size_t)nN * sizeof(int), hipMemcpyDeviceToDevice, stream);
    fill_kernel<<<(nE + 255) / 256, 256, 0, stream>>>(src, dst, ea, deg, csr, nE);

    // ---- weight prep (transpose + bf16) ----
    prep_w<64><<<(128 * 128 + 255) / 256, 256, 0, stream>>>(ws1, wn1, wt1);
    prep_w<128><<<(128 * 256 + 255) / 256, 256, 0, stream>>>(ws2, wn2, wt2);

    // ---- layer 0: agg x (5) into R1; h1 = conv(x, agg) -> R0 ----
    agg5_kernel<<<(nN + 255) / 256, 256, 0, stream>>>(x, rowptr, csr, R1, nN, nE);
    conv_mm<5, 64><<<512, 512, 0, stream>>>(x, R1, ws0, wn0, b0, R0, nN);

    // ---- layer 1: agg h1 (64) into R1; h2 = conv_mfma -> R2 ----
    aggD_kernel<64><<<(nN * 16 + 255) / 256, 256, 0, stream>>>(R0, rowptr, csr, R1, nN, nE);
    conv_mfma<64, false><<<nN / 64, 256, 0, stream>>>(R0, R1, wt1, b1, R2, nullptr, nullptr, nN);

    // ---- layer 2: agg h2 (128) into R0∪R1; conv_mfma with fused mean-pool ----
    aggD_kernel<128><<<(nN * 32 + 255) / 256, 256, 0, stream>>>(R2, rowptr, csr, agg128, nN, nE);
    hipMemsetAsync(sums, 0, ((size_t)nG * 128 + nG) * sizeof(float), stream);
    cnt_kernel<<<(nN + 255) / 256, 256, 0, stream>>>(bl, cnt, nN);
    conv_mfma<128, true><<<nN / 64, 256, 0, stream>>>(R2, agg128, wt2, b2, nullptr, bl, sums, nN);

    // ---- GRU x2 + decoder ----
    gru_kernel<<<B, 384, 0, stream>>>(sums, cnt, lmap,
                                      wih0, whh0, bih0, bhh0,
                                      wih1, whh1, bih1, bhh1,
                                      wdec, bdec, out, nG);
}

// Round 6
// 617.370 us; speedup vs baseline: 13.0452x; 1.4787x over previous
//
#include <hip/hip_runtime.h>
#include <cmath>

typedef __attribute__((ext_vector_type(8))) short short8b;
typedef __attribute__((ext_vector_type(4))) float floatx4;

__device__ __forceinline__ float sigm(float x) { return 1.0f / (1.0f + expf(-x)); }

// round-to-nearest-even f32 -> bf16 bits
__device__ __forceinline__ unsigned short f2bf(float f) {
    unsigned u = __float_as_uint(f);
    unsigned r = (u + 0x7FFFu + ((u >> 16) & 1u)) >> 16;
    return (unsigned short)r;
}

// ================= CSR build =================
__global__ __launch_bounds__(256)
void hist_kernel(const int* __restrict__ dst, int* __restrict__ deg, int nE)
{
    int i = blockIdx.x * blockDim.x + threadIdx.x;
    if (i < nE) atomicAdd(&deg[dst[i]], 1);
}

__global__ __launch_bounds__(256)
void scan_blocks(const int* __restrict__ in, int* __restrict__ out,
                 int* __restrict__ bsum, int n)
{
    __shared__ int sh[256];
    int base = blockIdx.x * 1024;
    int t = threadIdx.x;
    int v[4];
    int s = 0;
    #pragma unroll
    for (int q = 0; q < 4; ++q) {
        int idx = base + t * 4 + q;
        v[q] = (idx < n) ? in[idx] : 0;
        s += v[q];
    }
    sh[t] = s;
    __syncthreads();
    for (int off = 1; off < 256; off <<= 1) {
        int x = (t >= off) ? sh[t - off] : 0;
        __syncthreads();
        sh[t] += x;
        __syncthreads();
    }
    int run = (t == 0) ? 0 : sh[t - 1];
    #pragma unroll
    for (int q = 0; q < 4; ++q) {
        int idx = base + t * 4 + q;
        if (idx < n) out[idx] = run;
        run += v[q];
    }
    if (t == 255 && bsum) bsum[blockIdx.x] = sh[255];
}

__global__ __launch_bounds__(256)
void scan_add(int* __restrict__ out, const int* __restrict__ boff, int n)
{
    int i = blockIdx.x * blockDim.x + threadIdx.x;
    if (i < n) out[i] += boff[i >> 10];
}

// pack (src, w) into one int: src<<14 | round(w*16383)
__global__ __launch_bounds__(256)
void fill_kernel(const int* __restrict__ src, const int* __restrict__ dst,
                 const float* __restrict__ ea, int* __restrict__ cursor,
                 int* __restrict__ csr, int nE)
{
    int i = blockIdx.x * blockDim.x + threadIdx.x;
    if (i < nE) {
        int d = dst[i];
        int p = atomicAdd(&cursor[d], 1);
        int wq = __float2int_rn(ea[i] * 16383.f);
        csr[p] = (src[i] << 14) | wq;
    }
}

// ================= aggregation (gather) =================
__global__ __launch_bounds__(256)
void agg5_kernel(const float* __restrict__ x, const int* __restrict__ rowptr,
                 const int* __restrict__ csr, float* __restrict__ agg, int nN, int nE)
{
    int n = blockIdx.x * blockDim.x + threadIdx.x;
    if (n >= nN) return;
    int e0 = rowptr[n];
    int e1 = (n + 1 < nN) ? rowptr[n + 1] : nE;
    float a[5] = {0.f, 0.f, 0.f, 0.f, 0.f};
    for (int e = e0; e < e1; ++e) {
        int v = csr[e];
        int s = ((unsigned)v) >> 14;
        float w = (float)(v & 16383) * (1.f / 16383.f);
        const float* xr = x + (size_t)s * 5;
        #pragma unroll
        for (int f = 0; f < 5; ++f) a[f] += w * xr[f];
    }
    float* ar = agg + (size_t)n * 5;
    #pragma unroll
    for (int f = 0; f < 5; ++f) ar[f] = a[f];
}

template<int D>
__global__ __launch_bounds__(256)
void aggD_kernel(const float* __restrict__ h, const int* __restrict__ rowptr,
                 const int* __restrict__ csr, float* __restrict__ agg, int nN, int nE)
{
    constexpr int TPN = D / 4;
    int gid = blockIdx.x * blockDim.x + threadIdx.x;
    int c = gid & (TPN - 1);
    int n = gid / TPN;
    if (n >= nN) return;
    int e0 = rowptr[n];
    int e1 = (n + 1 < nN) ? rowptr[n + 1] : nE;
    float4 acc = {0.f, 0.f, 0.f, 0.f};
    for (int e = e0; e < e1; ++e) {
        int v = csr[e];
        int s = ((unsigned)v) >> 14;
        float w = (float)(v & 16383) * (1.f / 16383.f);
        const float4 hv = *(const float4*)(h + (size_t)s * D + c * 4);
        acc.x += w * hv.x; acc.y += w * hv.y;
        acc.z += w * hv.z; acc.w += w * hv.w;
    }
    *(float4*)(agg + (size_t)n * D + c * 4) = acc;
}

// -------- small conv (layer 0): out = relu(h@ws + agg@wn + b) --------
template<int DIN, int DOUT>
__global__ __launch_bounds__(512)
void conv_mm(const float* __restrict__ h, const float* __restrict__ agg,
             const float* __restrict__ ws, const float* __restrict__ wn,
             const float* __restrict__ bias, float* __restrict__ out, int nN)
{
    __shared__ __align__(16) float s_w[2 * DIN * DOUT];
    __shared__ __align__(16) float s_b[DOUT];
    for (int i = threadIdx.x; i < DIN * DOUT; i += 512) {
        s_w[i] = ws[i];
        s_w[DIN * DOUT + i] = wn[i];
    }
    for (int i = threadIdx.x; i < DOUT; i += 512) s_b[i] = bias[i];
    __syncthreads();

    constexpr int TPN = DOUT / 4;
    constexpr int HALF = 512 / TPN;
    constexpr int NPASS = HALF * 2;
    const int jj = (threadIdx.x % TPN) * 4;
    const int nsub = threadIdx.x / TPN;

    for (int base = blockIdx.x * NPASS; base < nN; base += gridDim.x * NPASS) {
        int n0 = base + nsub;
        int n1 = base + nsub + HALF;
        bool v0 = n0 < nN, v1 = n1 < nN;
        int n0c = v0 ? n0 : nN - 1;
        int n1c = v1 ? n1 : nN - 1;

        float acc0[4], acc1[4];
        #pragma unroll
        for (int q = 0; q < 4; ++q) { acc0[q] = s_b[jj + q]; acc1[q] = s_b[jj + q]; }

        const float* p0 = h + (size_t)n0c * DIN;
        const float* p1 = h + (size_t)n1c * DIN;
        const float* a0 = agg + (size_t)n0c * DIN;
        const float* a1 = agg + (size_t)n1c * DIN;

        for (int k = 0; k < DIN; ++k) {
            float xs0 = p0[k], xs1 = p1[k];
            const float4 w4 = *(const float4*)(s_w + (size_t)k * DOUT + jj);
            acc0[0] += xs0 * w4.x; acc0[1] += xs0 * w4.y;
            acc0[2] += xs0 * w4.z; acc0[3] += xs0 * w4.w;
            acc1[0] += xs1 * w4.x; acc1[1] += xs1 * w4.y;
            acc1[2] += xs1 * w4.z; acc1[3] += xs1 * w4.w;
        }
        for (int k = 0; k < DIN; ++k) {
            float xs0 = a0[k], xs1 = a1[k];
            const float4 w4 = *(const float4*)(s_w + (size_t)(DIN + k) * DOUT + jj);
            acc0[0] += xs0 * w4.x; acc0[1] += xs0 * w4.y;
            acc0[2] += xs0 * w4.z; acc0[3] += xs0 * w4.w;
            acc1[0] += xs1 * w4.x; acc1[1] += xs1 * w4.y;
            acc1[2] += xs1 * w4.z; acc1[3] += xs1 * w4.w;
        }
        if (v0) {
            float4 o;
            o.x = fmaxf(acc0[0], 0.f); o.y = fmaxf(acc0[1], 0.f);
            o.z = fmaxf(acc0[2], 0.f); o.w = fmaxf(acc0[3], 0.f);
            *(float4*)(out + (size_t)n0 * DOUT + jj) = o;
        }
        if (v1) {
            float4 o;
            o.x = fmaxf(acc1[0], 0.f); o.y = fmaxf(acc1[1], 0.f);
            o.z = fmaxf(acc1[2], 0.f); o.w = fmaxf(acc1[3], 0.f);
            *(float4*)(out + (size_t)n1 * DOUT + jj) = o;
        }
    }
}

// -------- weight prep: Wt[col][k] bf16, k = [self(DIN) | nei(DIN)] --------
template<int DIN>
__global__ __launch_bounds__(256)
void prep_w(const float* __restrict__ ws, const float* __restrict__ wn,
            unsigned short* __restrict__ wt)
{
    constexpr int KC = 2 * DIN;
    int idx = blockIdx.x * 256 + threadIdx.x;
    if (idx >= 128 * KC) return;
    int col = idx / KC, k = idx % KC;
    float v = (k < DIN) ? ws[(size_t)k * 128 + col] : wn[(size_t)(k - DIN) * 128 + col];
    wt[(size_t)col * KC + k] = f2bf(v);
}

// -------- big conv via MFMA: out = relu([h|agg] @ [ws;wn] + b) --------
// block: 256 thr / 4 waves; 64-node tile; wave tile = 32 nodes x 64 cols.
// POOL: block-local segmented reduction (labels sorted), then few atomics.
template<int DIN, bool POOL>
__global__ __launch_bounds__(256)
void conv_mfma(const float* __restrict__ h, const float* __restrict__ agg,
               const unsigned short* __restrict__ wt,   // [128][2*DIN] bf16
               const float* __restrict__ bias, float* __restrict__ out,
               const int* __restrict__ bl, float* __restrict__ sums, int nN)
{
    constexpr int KC = 2 * DIN;
    constexpr int NPANEL = KC / 64;
    constexpr int LDK = 72;     // padded row stride (ushorts), 144B
    // smem layout: [A: 64*72*2 = 9216][B: 128*72*2 = 18432]  (27648 B)
    // POOL overlay (after compute): [out tile: 64*129*4 = 33024][labels: 256]
    constexpr int SMEM_BYTES = POOL ? 33280 : 27648;
    __shared__ __align__(16) unsigned char smem[SMEM_BYTES];
    unsigned short* sA = (unsigned short*)smem;
    unsigned short* sB = (unsigned short*)(smem + 9216);

    const int tid  = threadIdx.x;
    const int lane = tid & 63;
    const int w    = tid >> 6;
    const int nb   = (w >> 1) * 32;   // wave node base (0 or 32)
    const int cb   = (w & 1) * 64;    // wave col base (0 or 64)
    const int r15  = lane & 15;
    const int k8   = (lane >> 4) * 8;
    const int tile0 = blockIdx.x * 64;            // nN % 64 == 0

    const floatx4 zero4 = {0.f, 0.f, 0.f, 0.f};
    floatx4 acc[2][4];
    #pragma unroll
    for (int m = 0; m < 2; ++m)
        #pragma unroll
        for (int n = 0; n < 4; ++n) acc[m][n] = zero4;

    for (int kp = 0; kp < NPANEL; ++kp) {
        const int kbase = kp * 64;
        const float* M = (kbase < DIN) ? h : agg;
        const int koff = (kbase < DIN) ? kbase : (kbase - DIN);
        // stage A: 64 nodes x 64 k (f32 -> bf16)
        #pragma unroll
        for (int r = 0; r < 4; ++r) {
            int f = tid + r * 256;
            int node = f >> 4, kq = f & 15;
            float4 v = *(const float4*)(M + (size_t)(tile0 + node) * DIN + koff + kq * 4);
            ushort4 o;
            o.x = f2bf(v.x); o.y = f2bf(v.y); o.z = f2bf(v.z); o.w = f2bf(v.w);
            *(ushort4*)(&sA[node * LDK + kq * 4]) = o;
        }
        // stage B: 128 cols x 64 k (already bf16)
        #pragma unroll
        for (int r = 0; r < 8; ++r) {
            int f = tid + r * 256;
            int col = f >> 4, kq = f & 15;
            *(ushort4*)(&sB[col * LDK + kq * 4]) =
                *(const ushort4*)(wt + (size_t)col * KC + kbase + kq * 4);
        }
        __syncthreads();
        #pragma unroll
        for (int ks = 0; ks < 2; ++ks) {
            const int kk = ks * 32 + k8;
            short8b a0 = *(const short8b*)(&sA[(nb + r15) * LDK + kk]);
            short8b a1 = *(const short8b*)(&sA[(nb + 16 + r15) * LDK + kk]);
            #pragma unroll
            for (int n = 0; n < 4; ++n) {
                short8b b = *(const short8b*)(&sB[(cb + n * 16 + r15) * LDK + kk]);
                acc[0][n] = __builtin_amdgcn_mfma_f32_16x16x32_bf16(a0, b, acc[0][n], 0, 0, 0);
                acc[1][n] = __builtin_amdgcn_mfma_f32_16x16x32_bf16(a1, b, acc[1][n], 0, 0, 0);
            }
        }
        __syncthreads();
    }

    // epilogue: C/D layout col=lane&15, row=(lane>>4)*4+j
    const int row4 = (lane >> 4) * 4;
    if constexpr (POOL) {
        // write relu'd tile to LDS (overlay, sA/sB dead after final barrier)
        float* s_out = (float*)smem;          // [64][129]
        int*   s_gl  = (int*)(smem + 33024);  // [64]
        #pragma unroll
        for (int n = 0; n < 4; ++n) {
            const int col = cb + n * 16 + r15;
            const float bv = bias[col];
            #pragma unroll
            for (int m = 0; m < 2; ++m) {
                #pragma unroll
                for (int j = 0; j < 4; ++j) {
                    int row = nb + m * 16 + row4 + j;
                    s_out[row * 129 + col] = fmaxf(acc[m][n][j] + bv, 0.f);
                }
            }
        }
        if (tid < 64) s_gl[tid] = bl[tile0 + tid];
        __syncthreads();
        // segmented flush: 2 threads per col, 32 rows each; labels sorted ->
        // one atomic per (graph-run, col)
        {
            const int col  = tid & 127;
            const int r0   = (tid >> 7) * 32;
            float run = 0.f;
            int gprev = s_gl[r0];
            for (int r = r0; r < r0 + 32; ++r) {
                int g = s_gl[r];
                float v = s_out[r * 129 + col];
                if (g != gprev) {
                    unsafeAtomicAdd(&sums[(size_t)gprev * 128 + col], run);
                    run = v;
                    gprev = g;
                } else {
                    run += v;
                }
            }
            unsafeAtomicAdd(&sums[(size_t)gprev * 128 + col], run);
        }
    } else {
        #pragma unroll
        for (int n = 0; n < 4; ++n) {
            const int col = cb + n * 16 + r15;
            const float bv = bias[col];
            #pragma unroll
            for (int m = 0; m < 2; ++m) {
                #pragma unroll
                for (int j = 0; j < 4; ++j) {
                    int node = tile0 + nb + m * 16 + row4 + j;
                    out[(size_t)node * 128 + col] = fmaxf(acc[m][n][j] + bv, 0.f);
                }
            }
        }
    }
}

// ---------------- per-graph node counts (binary search, no atomics) ----------------
__global__ __launch_bounds__(256)
void cnt_bs(const int* __restrict__ bl, float* __restrict__ cnt, int nN, int nG)
{
    int g = blockIdx.x * blockDim.x + threadIdx.x;
    if (g >= nG) return;
    int lo = 0, hi = nN;
    while (lo < hi) { int mid = (lo + hi) >> 1; if (bl[mid] < g) lo = mid + 1; else hi = mid; }
    int s = lo;
    hi = nN;
    while (lo < hi) { int mid = (lo + hi) >> 1; if (bl[mid] < g + 1) lo = mid + 1; else hi = mid; }
    cnt[g] = (float)(lo - s);
}

// ---------------- GRU (2 layers) + decoder, one block per sequence ----------------
__global__ __launch_bounds__(384)
void gru_kernel(const float* __restrict__ sums, const float* __restrict__ cnt,
                const int* __restrict__ lmap,
                const float* __restrict__ wih0, const float* __restrict__ whh0,
                const float* __restrict__ bih0, const float* __restrict__ bhh0,
                const float* __restrict__ wih1, const float* __restrict__ whh1,
                const float* __restrict__ bih1, const float* __restrict__ bhh1,
                const float* __restrict__ wdec, const float* __restrict__ bdec,
                float* __restrict__ out, int nG)
{
    __shared__ __align__(16) float s_x[16][128];
    __shared__ __align__(16) float s_xp[16][384];
    __shared__ __align__(16) float s_h[128];
    __shared__ __align__(16) float s_gh[384];

    const int b = blockIdx.x;
    const int tid = threadIdx.x;

    for (int i = tid; i < 16 * 128; i += 384) {
        int t = i >> 7, j = i & 127;
        int g = lmap[b * 16 + t];
        s_x[t][j] = sums[(size_t)g * 128 + j] / fmaxf(cnt[g], 1.0f);
    }
    __syncthreads();

    for (int layer = 0; layer < 2; ++layer) {
        const float* wih = layer ? wih1 : wih0;
        const float* whh = layer ? whh1 : whh0;
        const float* bih = layer ? bih1 : bih0;
        const float* bhh = layer ? bhh1 : bhh0;

        {
            const int g = tid;
            float acc[16];
            #pragma unroll
            for (int t = 0; t < 16; ++t) acc[t] = 0.f;
            for (int kc = 0; kc < 32; ++kc) {
                float4 w = *(const float4*)(wih + (size_t)g * 128 + kc * 4);
                #pragma unroll
                for (int t = 0; t < 16; ++t) {
                    float4 xv = *(const float4*)&s_x[t][kc * 4];
                    acc[t] += w.x * xv.x + w.y * xv.y + w.z * xv.z + w.w * xv.w;
                }
            }
            float bg = bih[g];
            #pragma unroll
            for (int t = 0; t < 16; ++t) s_xp[t][g] = acc[t] + bg;
        }
        __syncthreads();
        if (tid < 128) s_h[tid] = 0.f;
        __syncthreads();

        for (int t = 0; t < 16; ++t) {
            {
                const int g = tid;
                float acc = bhh[g];
                for (int kc = 0; kc < 32; ++kc) {
                    float4 w = *(const float4*)(whh + (size_t)g * 128 + kc * 4);
                    float4 hv = *(const float4*)&s_h[kc * 4];
                    acc += w.x * hv.x + w.y * hv.y + w.z * hv.z + w.w * hv.w;
                }
                s_gh[g] = acc;
            }
            __syncthreads();
            if (tid < 128) {
                int j = tid;
                float r = sigm(s_xp[t][j] + s_gh[j]);
                float z = sigm(s_xp[t][128 + j] + s_gh[128 + j]);
                float n = tanhf(s_xp[t][256 + j] + r * s_gh[256 + j]);
                float hn = (1.f - z) * n + z * s_h[j];
                s_h[j] = hn;
                s_x[t][j] = hn;
            }
            __syncthreads();
        }
    }

    if (tid < 16) {
        float acc = bdec[0];
        const float* o = &s_x[tid][0];
        for (int j = 0; j < 128; ++j) acc += o[j] * wdec[j];
        float p = sigm(acc);
        out[b * 16 + tid] = p;
        if (tid == 15) out[nG + b] = p;
    }
}

extern "C" void kernel_launch(void* const* d_in, const int* in_sizes, int n_in,
                              void* d_out, int out_size, void* d_ws, size_t ws_size,
                              hipStream_t stream)
{
    const float* x    = (const float*)d_in[0];
    const float* ea   = (const float*)d_in[1];
    const int*   ei   = (const int*)d_in[2];
    const int*   bl   = (const int*)d_in[3];
    const int*   lmap = (const int*)d_in[4];
    const float* ws0 = (const float*)d_in[5];
    const float* wn0 = (const float*)d_in[6];
    const float* b0  = (const float*)d_in[7];
    const float* ws1 = (const float*)d_in[8];
    const float* wn1 = (const float*)d_in[9];
    const float* b1  = (const float*)d_in[10];
    const float* ws2 = (const float*)d_in[11];
    const float* wn2 = (const float*)d_in[12];
    const float* b2  = (const float*)d_in[13];
    const float* wih0 = (const float*)d_in[14];
    const float* whh0 = (const float*)d_in[15];
    const float* bih0 = (const float*)d_in[16];
    const float* bhh0 = (const float*)d_in[17];
    const float* wih1 = (const float*)d_in[18];
    const float* whh1 = (const float*)d_in[19];
    const float* bih1 = (const float*)d_in[20];
    const float* bhh1 = (const float*)d_in[21];
    const float* wdec = (const float*)d_in[22];
    const float* bdec = (const float*)d_in[23];
    float* out = (float*)d_out;

    const int nN = in_sizes[0] / 5;     // 200000
    const int nE = in_sizes[1];         // 1600000
    const int nG = in_sizes[4];         // 4096
    const int B  = nG / 16;             // 256

    const int* src = ei;
    const int* dst = ei + nE;

    float* R0   = (float*)d_ws;
    float* R1   = R0 + (size_t)nN * 64;
    float* R2   = R1 + (size_t)nN * 64;
    float* sums = R2 + (size_t)nN * 128;
    float* cnt  = sums + (size_t)nG * 128;
    int* deg    = (int*)(cnt + nG);
    int* rowptr = deg + nN;
    int* bsum   = rowptr + nN;
    int* boff   = bsum + 256;
    int* csr    = boff + 256;
    unsigned short* wt1 = (unsigned short*)(csr + nE);   // [128][128] bf16
    unsigned short* wt2 = wt1 + 128 * 128;               // [128][256] bf16
    float* agg128 = R0;

    const int nblocks_scan = (nN + 1023) / 1024;

    // ---- build CSR (dst-sorted edges), reused by all 3 layers ----
    hipMemsetAsync(deg, 0, (size_t)nN * sizeof(int), stream);
    hist_kernel<<<(nE + 255) / 256, 256, 0, stream>>>(dst, deg, nE);
    scan_blocks<<<nblocks_scan, 256, 0, stream>>>(deg, rowptr, bsum, nN);
    scan_blocks<<<1, 256, 0, stream>>>(bsum, boff, nullptr, nblocks_scan);
    scan_add<<<(nN + 255) / 256, 256, 0, stream>>>(rowptr, boff, nN);
    hipMemcpyAsync(deg, rowptr, (size_t)nN * sizeof(int), hipMemcpyDeviceToDevice, stream);
    fill_kernel<<<(nE + 255) / 256, 256, 0, stream>>>(src, dst, ea, deg, csr, nE);

    // ---- weight prep (transpose + bf16) ----
    prep_w<64><<<(128 * 128 + 255) / 256, 256, 0, stream>>>(ws1, wn1, wt1);
    prep_w<128><<<(128 * 256 + 255) / 256, 256, 0, stream>>>(ws2, wn2, wt2);

    // ---- layer 0: agg x (5) into R1; h1 = conv(x, agg) -> R0 ----
    agg5_kernel<<<(nN + 255) / 256, 256, 0, stream>>>(x, rowptr, csr, R1, nN, nE);
    conv_mm<5, 64><<<512, 512, 0, stream>>>(x, R1, ws0, wn0, b0, R0, nN);

    // ---- layer 1: agg h1 (64) into R1; h2 = conv_mfma -> R2 ----
    aggD_kernel<64><<<(nN * 16 + 255) / 256, 256, 0, stream>>>(R0, rowptr, csr, R1, nN, nE);
    conv_mfma<64, false><<<nN / 64, 256, 0, stream>>>(R0, R1, wt1, b1, R2, nullptr, nullptr, nN);

    // ---- layer 2: agg h2 (128) into R0∪R1; conv_mfma with fused pooled sums ----
    aggD_kernel<128><<<(nN * 32 + 255) / 256, 256, 0, stream>>>(R2, rowptr, csr, agg128, nN, nE);
    hipMemsetAsync(sums, 0, (size_t)nG * 128 * sizeof(float), stream);
    cnt_bs<<<(nG + 255) / 256, 256, 0, stream>>>(bl, cnt, nN, nG);
    conv_mfma<128, true><<<nN / 64, 256, 0, stream>>>(R2, agg128, wt2, b2, nullptr, bl, sums, nN);

    // ---- GRU x2 + decoder ----
    gru_kernel<<<B, 384, 0, stream>>>(sums, cnt, lmap,
                                      wih0, whh0, bih0, bhh0,
                                      wih1, whh1, bih1, bhh1,
                                      wdec, bdec, out, nG);
}

// Round 7
// 500.634 us; speedup vs baseline: 16.0870x; 1.2332x over previous
//
#include <hip/hip_runtime.h>
#include <cmath>

typedef __attribute__((ext_vector_type(8))) short short8b;
typedef __attribute__((ext_vector_type(8))) unsigned short ushort8b;
typedef __attribute__((ext_vector_type(4))) float floatx4;

__device__ __forceinline__ float sigm(float x) { return 1.0f / (1.0f + expf(-x)); }

// round-to-nearest-even f32 -> bf16 bits
__device__ __forceinline__ unsigned short f2bf(float f) {
    unsigned u = __float_as_uint(f);
    unsigned r = (u + 0x7FFFu + ((u >> 16) & 1u)) >> 16;
    return (unsigned short)r;
}
__device__ __forceinline__ float bf2f(unsigned short b) {
    return __uint_as_float(((unsigned)b) << 16);
}

// ================= CSR build =================
__global__ __launch_bounds__(256)
void hist_kernel(const int* __restrict__ dst, int* __restrict__ deg, int nE)
{
    int i = blockIdx.x * blockDim.x + threadIdx.x;
    if (i < nE) atomicAdd(&deg[dst[i]], 1);
}

__global__ __launch_bounds__(256)
void scan_blocks(const int* __restrict__ in, int* __restrict__ out,
                 int* __restrict__ bsum, int n)
{
    __shared__ int sh[256];
    int base = blockIdx.x * 1024;
    int t = threadIdx.x;
    int v[4];
    int s = 0;
    #pragma unroll
    for (int q = 0; q < 4; ++q) {
        int idx = base + t * 4 + q;
        v[q] = (idx < n) ? in[idx] : 0;
        s += v[q];
    }
    sh[t] = s;
    __syncthreads();
    for (int off = 1; off < 256; off <<= 1) {
        int x = (t >= off) ? sh[t - off] : 0;
        __syncthreads();
        sh[t] += x;
        __syncthreads();
    }
    int run = (t == 0) ? 0 : sh[t - 1];
    #pragma unroll
    for (int q = 0; q < 4; ++q) {
        int idx = base + t * 4 + q;
        if (idx < n) out[idx] = run;
        run += v[q];
    }
    if (t == 255 && bsum) bsum[blockIdx.x] = sh[255];
}

__global__ __launch_bounds__(256)
void scan_add(int* __restrict__ out, const int* __restrict__ boff, int n)
{
    int i = blockIdx.x * blockDim.x + threadIdx.x;
    if (i < n) out[i] += boff[i >> 10];
}

// pack (src, w) into one int: src<<14 | round(w*16383)
__global__ __launch_bounds__(256)
void fill_kernel(const int* __restrict__ src, const int* __restrict__ dst,
                 const float* __restrict__ ea, int* __restrict__ cursor,
                 int* __restrict__ csr, int nE)
{
    int i = blockIdx.x * blockDim.x + threadIdx.x;
    if (i < nE) {
        int d = dst[i];
        int p = atomicAdd(&cursor[d], 1);
        int wq = __float2int_rn(ea[i] * 16383.f);
        csr[p] = (src[i] << 14) | wq;
    }
}

// ================= aggregation (gather) =================
__global__ __launch_bounds__(256)
void agg5_kernel(const float* __restrict__ x, const int* __restrict__ rowptr,
                 const int* __restrict__ csr, float* __restrict__ agg, int nN, int nE)
{
    int n = blockIdx.x * blockDim.x + threadIdx.x;
    if (n >= nN) return;
    int e0 = rowptr[n];
    int e1 = (n + 1 < nN) ? rowptr[n + 1] : nE;
    float a[5] = {0.f, 0.f, 0.f, 0.f, 0.f};
    for (int e = e0; e < e1; ++e) {
        int v = csr[e];
        int s = ((unsigned)v) >> 14;
        float w = (float)(v & 16383) * (1.f / 16383.f);
        const float* xr = x + (size_t)s * 5;
        #pragma unroll
        for (int f = 0; f < 5; ++f) a[f] += w * xr[f];
    }
    float* ar = agg + (size_t)n * 5;
    #pragma unroll
    for (int f = 0; f < 5; ++f) ar[f] = a[f];
}

// bf16 gather: agg[n] = sum_e w_e * h[src_e], 8 cols per thread (ushort8 = 16B)
template<int D>
__global__ __launch_bounds__(256)
void aggD_bf16(const unsigned short* __restrict__ h, const int* __restrict__ rowptr,
               const int* __restrict__ csr, unsigned short* __restrict__ agg,
               int nN, int nE)
{
    constexpr int TPN = D / 8;             // 8 or 16 threads per node
    int gid = blockIdx.x * blockDim.x + threadIdx.x;
    int c = gid & (TPN - 1);
    int n = gid / TPN;
    if (n >= nN) return;
    int e0 = rowptr[n];
    int e1 = (n + 1 < nN) ? rowptr[n + 1] : nE;
    float acc[8] = {0.f, 0.f, 0.f, 0.f, 0.f, 0.f, 0.f, 0.f};
    for (int e = e0; e < e1; ++e) {
        int v = csr[e];
        int s = ((unsigned)v) >> 14;
        float w = (float)(v & 16383) * (1.f / 16383.f);
        const ushort8b hv = *(const ushort8b*)(h + (size_t)s * D + c * 8);
        #pragma unroll
        for (int q = 0; q < 8; ++q) acc[q] += w * bf2f(hv[q]);
    }
    ushort8b o;
    #pragma unroll
    for (int q = 0; q < 8; ++q) o[q] = f2bf(acc[q]);
    *(ushort8b*)(agg + (size_t)n * D + c * 8) = o;
}

// -------- small conv (layer 0): out_bf16 = relu(x@ws + agg@wn + b) --------
template<int DIN, int DOUT>
__global__ __launch_bounds__(512)
void conv_mm(const float* __restrict__ h, const float* __restrict__ agg,
             const float* __restrict__ ws, const float* __restrict__ wn,
             const float* __restrict__ bias, unsigned short* __restrict__ out, int nN)
{
    __shared__ __align__(16) float s_w[2 * DIN * DOUT];
    __shared__ __align__(16) float s_b[DOUT];
    for (int i = threadIdx.x; i < DIN * DOUT; i += 512) {
        s_w[i] = ws[i];
        s_w[DIN * DOUT + i] = wn[i];
    }
    for (int i = threadIdx.x; i < DOUT; i += 512) s_b[i] = bias[i];
    __syncthreads();

    constexpr int TPN = DOUT / 4;
    constexpr int HALF = 512 / TPN;
    constexpr int NPASS = HALF * 2;
    const int jj = (threadIdx.x % TPN) * 4;
    const int nsub = threadIdx.x / TPN;

    for (int base = blockIdx.x * NPASS; base < nN; base += gridDim.x * NPASS) {
        int n0 = base + nsub;
        int n1 = base + nsub + HALF;
        bool v0 = n0 < nN, v1 = n1 < nN;
        int n0c = v0 ? n0 : nN - 1;
        int n1c = v1 ? n1 : nN - 1;

        float acc0[4], acc1[4];
        #pragma unroll
        for (int q = 0; q < 4; ++q) { acc0[q] = s_b[jj + q]; acc1[q] = s_b[jj + q]; }

        const float* p0 = h + (size_t)n0c * DIN;
        const float* p1 = h + (size_t)n1c * DIN;
        const float* a0 = agg + (size_t)n0c * DIN;
        const float* a1 = agg + (size_t)n1c * DIN;

        for (int k = 0; k < DIN; ++k) {
            float xs0 = p0[k], xs1 = p1[k];
            const float4 w4 = *(const float4*)(s_w + (size_t)k * DOUT + jj);
            acc0[0] += xs0 * w4.x; acc0[1] += xs0 * w4.y;
            acc0[2] += xs0 * w4.z; acc0[3] += xs0 * w4.w;
            acc1[0] += xs1 * w4.x; acc1[1] += xs1 * w4.y;
            acc1[2] += xs1 * w4.z; acc1[3] += xs1 * w4.w;
        }
        for (int k = 0; k < DIN; ++k) {
            float xs0 = a0[k], xs1 = a1[k];
            const float4 w4 = *(const float4*)(s_w + (size_t)(DIN + k) * DOUT + jj);
            acc0[0] += xs0 * w4.x; acc0[1] += xs0 * w4.y;
            acc0[2] += xs0 * w4.z; acc0[3] += xs0 * w4.w;
            acc1[0] += xs1 * w4.x; acc1[1] += xs1 * w4.y;
            acc1[2] += xs1 * w4.z; acc1[3] += xs1 * w4.w;
        }
        if (v0) {
            ushort4 o;
            o.x = f2bf(fmaxf(acc0[0], 0.f)); o.y = f2bf(fmaxf(acc0[1], 0.f));
            o.z = f2bf(fmaxf(acc0[2], 0.f)); o.w = f2bf(fmaxf(acc0[3], 0.f));
            *(ushort4*)(out + (size_t)n0 * DOUT + jj) = o;
        }
        if (v1) {
            ushort4 o;
            o.x = f2bf(fmaxf(acc1[0], 0.f)); o.y = f2bf(fmaxf(acc1[1], 0.f));
            o.z = f2bf(fmaxf(acc1[2], 0.f)); o.w = f2bf(fmaxf(acc1[3], 0.f));
            *(ushort4*)(out + (size_t)n1 * DOUT + jj) = o;
        }
    }
}

// -------- weight prep: Wt[col][k] bf16, k = [self(DIN) | nei(DIN)] --------
template<int DIN>
__global__ __launch_bounds__(256)
void prep_w(const float* __restrict__ ws, const float* __restrict__ wn,
            unsigned short* __restrict__ wt)
{
    constexpr int KC = 2 * DIN;
    int idx = blockIdx.x * 256 + threadIdx.x;
    if (idx >= 128 * KC) return;
    int col = idx / KC, k = idx % KC;
    float v = (k < DIN) ? ws[(size_t)k * 128 + col] : wn[(size_t)(k - DIN) * 128 + col];
    wt[(size_t)col * KC + k] = f2bf(v);
}

// -------- big conv via MFMA: out = relu([h|agg] @ [ws;wn] + b), bf16 in/out --------
// block: 256 thr / 4 waves; 64-node tile; wave tile = 32 nodes x 64 cols.
// POOL: block-local segmented reduction (labels sorted), then few atomics.
template<int DIN, bool POOL>
__global__ __launch_bounds__(256)
void conv_mfma(const unsigned short* __restrict__ h, const unsigned short* __restrict__ agg,
               const unsigned short* __restrict__ wt,   // [128][2*DIN] bf16
               const float* __restrict__ bias, unsigned short* __restrict__ out,
               const int* __restrict__ bl, float* __restrict__ sums, int nN)
{
    constexpr int KC = 2 * DIN;
    constexpr int NPANEL = KC / 64;
    constexpr int LDK = 72;     // padded row stride (ushorts), 144B (16B mult)
    // smem: [A: 64*72*2 = 9216][B: 128*72*2 = 18432]  (27648 B)
    // POOL overlay (after compute): [out tile: 64*129*4 = 33024][labels: 256]
    constexpr int SMEM_BYTES = POOL ? 33280 : 27648;
    __shared__ __align__(16) unsigned char smem[SMEM_BYTES];
    unsigned short* sA = (unsigned short*)smem;
    unsigned short* sB = (unsigned short*)(smem + 9216);

    const int tid  = threadIdx.x;
    const int lane = tid & 63;
    const int w    = tid >> 6;
    const int nb   = (w >> 1) * 32;   // wave node base (0 or 32)
    const int cb   = (w & 1) * 64;    // wave col base (0 or 64)
    const int r15  = lane & 15;
    const int k8   = (lane >> 4) * 8;
    const int tile0 = blockIdx.x * 64;            // nN % 64 == 0

    const floatx4 zero4 = {0.f, 0.f, 0.f, 0.f};
    floatx4 acc[2][4];
    #pragma unroll
    for (int m = 0; m < 2; ++m)
        #pragma unroll
        for (int n = 0; n < 4; ++n) acc[m][n] = zero4;

    for (int kp = 0; kp < NPANEL; ++kp) {
        const int kbase = kp * 64;
        const unsigned short* M = (kbase < DIN) ? h : agg;
        const int koff = (kbase < DIN) ? kbase : (kbase - DIN);
        // stage A: 64 nodes x 64 k (bf16 copy, ushort8 = 16B)
        #pragma unroll
        for (int r = 0; r < 2; ++r) {
            int f = tid + r * 256;
            int node = f >> 3, kq = f & 7;
            *(ushort8b*)(&sA[node * LDK + kq * 8]) =
                *(const ushort8b*)(M + (size_t)(tile0 + node) * DIN + koff + kq * 8);
        }
        // stage B: 128 cols x 64 k
        #pragma unroll
        for (int r = 0; r < 4; ++r) {
            int f = tid + r * 256;
            int col = f >> 3, kq = f & 7;
            *(ushort8b*)(&sB[col * LDK + kq * 8]) =
                *(const ushort8b*)(wt + (size_t)col * KC + kbase + kq * 8);
        }
        __syncthreads();
        #pragma unroll
        for (int ks = 0; ks < 2; ++ks) {
            const int kk = ks * 32 + k8;
            short8b a0 = *(const short8b*)(&sA[(nb + r15) * LDK + kk]);
            short8b a1 = *(const short8b*)(&sA[(nb + 16 + r15) * LDK + kk]);
            #pragma unroll
            for (int n = 0; n < 4; ++n) {
                short8b b = *(const short8b*)(&sB[(cb + n * 16 + r15) * LDK + kk]);
                acc[0][n] = __builtin_amdgcn_mfma_f32_16x16x32_bf16(a0, b, acc[0][n], 0, 0, 0);
                acc[1][n] = __builtin_amdgcn_mfma_f32_16x16x32_bf16(a1, b, acc[1][n], 0, 0, 0);
            }
        }
        __syncthreads();
    }

    // epilogue: C/D layout col=lane&15, row=(lane>>4)*4+j
    const int row4 = (lane >> 4) * 4;
    if constexpr (POOL) {
        float* s_out = (float*)smem;          // [64][129]
        int*   s_gl  = (int*)(smem + 33024);  // [64]
        #pragma unroll
        for (int n = 0; n < 4; ++n) {
            const int col = cb + n * 16 + r15;
            const float bv = bias[col];
            #pragma unroll
            for (int m = 0; m < 2; ++m) {
                #pragma unroll
                for (int j = 0; j < 4; ++j) {
                    int row = nb + m * 16 + row4 + j;
                    s_out[row * 129 + col] = fmaxf(acc[m][n][j] + bv, 0.f);
                }
            }
        }
        if (tid < 64) s_gl[tid] = bl[tile0 + tid];
        __syncthreads();
        // segmented flush: 2 threads per col, 32 rows each
        {
            const int col  = tid & 127;
            const int r0   = (tid >> 7) * 32;
            float run = 0.f;
            int gprev = s_gl[r0];
            for (int r = r0; r < r0 + 32; ++r) {
                int g = s_gl[r];
                float v = s_out[r * 129 + col];
                if (g != gprev) {
                    unsafeAtomicAdd(&sums[(size_t)gprev * 128 + col], run);
                    run = v;
                    gprev = g;
                } else {
                    run += v;
                }
            }
            unsafeAtomicAdd(&sums[(size_t)gprev * 128 + col], run);
        }
    } else {
        #pragma unroll
        for (int n = 0; n < 4; ++n) {
            const int col = cb + n * 16 + r15;
            const float bv = bias[col];
            #pragma unroll
            for (int m = 0; m < 2; ++m) {
                #pragma unroll
                for (int j = 0; j < 4; ++j) {
                    int node = tile0 + nb + m * 16 + row4 + j;
                    out[(size_t)node * 128 + col] = f2bf(fmaxf(acc[m][n][j] + bv, 0.f));
                }
            }
        }
    }
}

// ---------------- per-graph node counts (binary search, no atomics) ----------------
__global__ __launch_bounds__(256)
void cnt_bs(const int* __restrict__ bl, float* __restrict__ cnt, int nN, int nG)
{
    int g = blockIdx.x * blockDim.x + threadIdx.x;
    if (g >= nG) return;
    int lo = 0, hi = nN;
    while (lo < hi) { int mid = (lo + hi) >> 1; if (bl[mid] < g) lo = mid + 1; else hi = mid; }
    int s = lo;
    hi = nN;
    while (lo < hi) { int mid = (lo + hi) >> 1; if (bl[mid] < g + 1) lo = mid + 1; else hi = mid; }
    cnt[g] = (float)(lo - s);
}

// ---------------- GRU (2 layers) + decoder, one block per sequence ----------------
__global__ __launch_bounds__(384)
void gru_kernel(const float* __restrict__ sums, const float* __restrict__ cnt,
                const int* __restrict__ lmap,
                const float* __restrict__ wih0, const float* __restrict__ whh0,
                const float* __restrict__ bih0, const float* __restrict__ bhh0,
                const float* __restrict__ wih1, const float* __restrict__ whh1,
                const float* __restrict__ bih1, const float* __restrict__ bhh1,
                const float* __restrict__ wdec, const float* __restrict__ bdec,
                float* __restrict__ out, int nG)
{
    __shared__ __align__(16) float s_x[16][128];
    __shared__ __align__(16) float s_xp[16][384];
    __shared__ __align__(16) float s_h[128];
    __shared__ __align__(16) float s_gh[384];

    const int b = blockIdx.x;
    const int tid = threadIdx.x;

    for (int i = tid; i < 16 * 128; i += 384) {
        int t = i >> 7, j = i & 127;
        int g = lmap[b * 16 + t];
        s_x[t][j] = sums[(size_t)g * 128 + j] / fmaxf(cnt[g], 1.0f);
    }
    __syncthreads();

    for (int layer = 0; layer < 2; ++layer) {
        const float* wih = layer ? wih1 : wih0;
        const float* whh = layer ? whh1 : whh0;
        const float* bih = layer ? bih1 : bih0;
        const float* bhh = layer ? bhh1 : bhh0;

        {
            const int g = tid;
            float acc[16];
            #pragma unroll
            for (int t = 0; t < 16; ++t) acc[t] = 0.f;
            for (int kc = 0; kc < 32; ++kc) {
                float4 w = *(const float4*)(wih + (size_t)g * 128 + kc * 4);
                #pragma unroll
                for (int t = 0; t < 16; ++t) {
                    float4 xv = *(const float4*)&s_x[t][kc * 4];
                    acc[t] += w.x * xv.x + w.y * xv.y + w.z * xv.z + w.w * xv.w;
                }
            }
            float bg = bih[g];
            #pragma unroll
            for (int t = 0; t < 16; ++t) s_xp[t][g] = acc[t] + bg;
        }
        __syncthreads();
        if (tid < 128) s_h[tid] = 0.f;
        __syncthreads();

        for (int t = 0; t < 16; ++t) {
            {
                const int g = tid;
                float acc = bhh[g];
                for (int kc = 0; kc < 32; ++kc) {
                    float4 w = *(const float4*)(whh + (size_t)g * 128 + kc * 4);
                    float4 hv = *(const float4*)&s_h[kc * 4];
                    acc += w.x * hv.x + w.y * hv.y + w.z * hv.z + w.w * hv.w;
                }
                s_gh[g] = acc;
            }
            __syncthreads();
            if (tid < 128) {
                int j = tid;
                float r = sigm(s_xp[t][j] + s_gh[j]);
                float z = sigm(s_xp[t][128 + j] + s_gh[128 + j]);
                float n = tanhf(s_xp[t][256 + j] + r * s_gh[256 + j]);
                float hn = (1.f - z) * n + z * s_h[j];
                s_h[j] = hn;
                s_x[t][j] = hn;
            }
            __syncthreads();
        }
    }

    if (tid < 16) {
        float acc = bdec[0];
        const float* o = &s_x[tid][0];
        for (int j = 0; j < 128; ++j) acc += o[j] * wdec[j];
        float p = sigm(acc);
        out[b * 16 + tid] = p;
        if (tid == 15) out[nG + b] = p;
    }
}

extern "C" void kernel_launch(void* const* d_in, const int* in_sizes, int n_in,
                              void* d_out, int out_size, void* d_ws, size_t ws_size,
                              hipStream_t stream)
{
    const float* x    = (const float*)d_in[0];
    const float* ea   = (const float*)d_in[1];
    const int*   ei   = (const int*)d_in[2];
    const int*   bl   = (const int*)d_in[3];
    const int*   lmap = (const int*)d_in[4];
    const float* ws0 = (const float*)d_in[5];
    const float* wn0 = (const float*)d_in[6];
    const float* b0  = (const float*)d_in[7];
    const float* ws1 = (const float*)d_in[8];
    const float* wn1 = (const float*)d_in[9];
    const float* b1  = (const float*)d_in[10];
    const float* ws2 = (const float*)d_in[11];
    const float* wn2 = (const float*)d_in[12];
    const float* b2  = (const float*)d_in[13];
    const float* wih0 = (const float*)d_in[14];
    const float* whh0 = (const float*)d_in[15];
    const float* bih0 = (const float*)d_in[16];
    const float* bhh0 = (const float*)d_in[17];
    const float* wih1 = (const float*)d_in[18];
    const float* whh1 = (const float*)d_in[19];
    const float* bih1 = (const float*)d_in[20];
    const float* bhh1 = (const float*)d_in[21];
    const float* wdec = (const float*)d_in[22];
    const float* bdec = (const float*)d_in[23];
    float* out = (float*)d_out;

    const int nN = in_sizes[0] / 5;     // 200000
    const int nE = in_sizes[1];         // 1600000
    const int nG = in_sizes[4];         // 4096
    const int B  = nG / 16;             // 256

    const int* src = ei;
    const int* dst = ei + nE;

    // Workspace (~115 MB): bf16 node buffers + f32 small stuff + CSR + weights
    unsigned short* R0   = (unsigned short*)d_ws;      // nN*64 bf16: h1, later agg128 lo
    unsigned short* R1   = R0 + (size_t)nN * 64;       // nN*64 bf16: agg64, later agg128 hi
    unsigned short* R2   = R1 + (size_t)nN * 64;       // nN*128 bf16: h2
    unsigned short* agg128b = R0;                      // alias R0∪R1 (contiguous nN*128)
    float* agg5 = (float*)(R2 + (size_t)nN * 128);     // nN*5 f32
    float* sums = agg5 + (size_t)nN * 5;               // nG*128 f32
    float* cnt  = sums + (size_t)nG * 128;
    int* deg    = (int*)(cnt + nG);
    int* rowptr = deg + nN;
    int* bsum   = rowptr + nN;
    int* boff   = bsum + 256;
    int* csr    = boff + 256;
    unsigned short* wt1 = (unsigned short*)(csr + nE); // [128][128] bf16
    unsigned short* wt2 = wt1 + 128 * 128;             // [128][256] bf16

    const int nblocks_scan = (nN + 1023) / 1024;

    // ---- build CSR (dst-sorted edges), reused by all 3 layers ----
    hipMemsetAsync(deg, 0, (size_t)nN * sizeof(int), stream);
    hist_kernel<<<(nE + 255) / 256, 256, 0, stream>>>(dst, deg, nE);
    scan_blocks<<<nblocks_scan, 256, 0, stream>>>(deg, rowptr, bsum, nN);
    scan_blocks<<<1, 256, 0, stream>>>(bsum, boff, nullptr, nblocks_scan);
    scan_add<<<(nN + 255) / 256, 256, 0, stream>>>(rowptr, boff, nN);
    hipMemcpyAsync(deg, rowptr, (size_t)nN * sizeof(int), hipMemcpyDeviceToDevice, stream);
    fill_kernel<<<(nE + 255) / 256, 256, 0, stream>>>(src, dst, ea, deg, csr, nE);

    // ---- weight prep (transpose + bf16) ----
    prep_w<64><<<(128 * 128 + 255) / 256, 256, 0, stream>>>(ws1, wn1, wt1);
    prep_w<128><<<(128 * 256 + 255) / 256, 256, 0, stream>>>(ws2, wn2, wt2);

    // ---- layer 0: agg x (5) -> agg5; h1 = conv(x, agg5) -> R0 (bf16) ----
    agg5_kernel<<<(nN + 255) / 256, 256, 0, stream>>>(x, rowptr, csr, agg5, nN, nE);
    conv_mm<5, 64><<<512, 512, 0, stream>>>(x, agg5, ws0, wn0, b0, R0, nN);

    // ---- layer 1: agg h1 (bf16) -> R1; h2 = conv_mfma -> R2 (bf16) ----
    aggD_bf16<64><<<(nN * 8 + 255) / 256, 256, 0, stream>>>(R0, rowptr, csr, R1, nN, nE);
    conv_mfma<64, false><<<nN / 64, 256, 0, stream>>>(R0, R1, wt1, b1, R2, nullptr, nullptr, nN);

    // ---- layer 2: agg h2 (bf16) -> agg128b; conv_mfma with fused pooled sums ----
    aggD_bf16<128><<<(nN * 16 + 255) / 256, 256, 0, stream>>>(R2, rowptr, csr, agg128b, nN, nE);
    hipMemsetAsync(sums, 0, (size_t)nG * 128 * sizeof(float), stream);
    cnt_bs<<<(nG + 255) / 256, 256, 0, stream>>>(bl, cnt, nN, nG);
    conv_mfma<128, true><<<nN / 64, 256, 0, stream>>>(R2, agg128b, wt2, b2, nullptr, bl, sums, nN);

    // ---- GRU x2 + decoder ----
    gru_kernel<<<B, 384, 0, stream>>>(sums, cnt, lmap,
                                      wih0, whh0, bih0, bhh0,
                                      wih1, whh1, bih1, bhh1,
                                      wdec, bdec, out, nG);
}

// Round 8
// 355.934 us; speedup vs baseline: 22.6269x; 1.4065x over previous
//
#include <hip/hip_runtime.h>
#include <cmath>

typedef __attribute__((ext_vector_type(8))) short short8b;
typedef __attribute__((ext_vector_type(8))) unsigned short ushort8b;
typedef __attribute__((ext_vector_type(4))) float floatx4;

__device__ __forceinline__ float sigm(float x) { return 1.0f / (1.0f + expf(-x)); }

__device__ __forceinline__ unsigned short f2bf(float f) {
    unsigned u = __float_as_uint(f);
    unsigned r = (u + 0x7FFFu + ((u >> 16) & 1u)) >> 16;
    return (unsigned short)r;
}
__device__ __forceinline__ float bf2f(unsigned short b) {
    return __uint_as_float(((unsigned)b) << 16);
}

// ================= CSR build: two-level binned counting sort =================
// buckets of 512 nodes: bucket = dst >> 9;  nBuck = ceil(nN/512) = 391

__global__ __launch_bounds__(512)
void bucket_hist(const int* __restrict__ dst, int* __restrict__ bcnt, int nE, int nBuck)
{
    __shared__ int h[512];
    const int t = threadIdx.x;
    h[t] = 0;
    __syncthreads();
    for (int i = blockIdx.x * 512 + t; i < nE; i += gridDim.x * 512)
        atomicAdd(&h[dst[i] >> 9], 1);
    __syncthreads();
    if (t < nBuck && h[t]) atomicAdd(&bcnt[t], h[t]);
}

// exclusive scan; block handles 1024 elements (4/thread)
__global__ __launch_bounds__(256)
void scan_blocks(const int* __restrict__ in, int* __restrict__ out,
                 int* __restrict__ bsum, int n)
{
    __shared__ int sh[256];
    int base = blockIdx.x * 1024;
    int t = threadIdx.x;
    int v[4];
    int s = 0;
    #pragma unroll
    for (int q = 0; q < 4; ++q) {
        int idx = base + t * 4 + q;
        v[q] = (idx < n) ? in[idx] : 0;
        s += v[q];
    }
    sh[t] = s;
    __syncthreads();
    for (int off = 1; off < 256; off <<= 1) {
        int x = (t >= off) ? sh[t - off] : 0;
        __syncthreads();
        sh[t] += x;
        __syncthreads();
    }
    int run = (t == 0) ? 0 : sh[t - 1];
    #pragma unroll
    for (int q = 0; q < 4; ++q) {
        int idx = base + t * 4 + q;
        if (idx < n) out[idx] = run;
        run += v[q];
    }
    if (t == 255 && bsum) bsum[blockIdx.x] = sh[255];
}

// bin edges into bucket regions: rec = { src<<14 | wq , dst&511 }
__global__ __launch_bounds__(512)
void bucket_scatter(const int* __restrict__ src, const int* __restrict__ dst,
                    const float* __restrict__ ea, int* __restrict__ bcur,
                    uint2* __restrict__ recs, int nE)
{
    __shared__ int hcnt[512];
    __shared__ int hbase[512];
    const int t = threadIdx.x;
    const int base = blockIdx.x * 8192;
    hcnt[t] = 0;
    __syncthreads();
    int eb[16], rank[16], dloc[16];
    #pragma unroll
    for (int q = 0; q < 16; ++q) {
        int e = base + q * 512 + t;
        if (e < nE) {
            int d = dst[e];
            eb[q] = d >> 9;
            dloc[q] = d & 511;
            rank[q] = atomicAdd(&hcnt[eb[q]], 1);
        }
    }
    __syncthreads();
    hbase[t] = hcnt[t] ? atomicAdd(&bcur[t], hcnt[t]) : 0;
    __syncthreads();
    #pragma unroll
    for (int q = 0; q < 16; ++q) {
        int e = base + q * 512 + t;
        if (e < nE) {
            int wq2 = __float2int_rn(ea[e] * 16383.f);
            uint2 r;
            r.x = (unsigned)((src[e] << 14) | wq2);
            r.y = (unsigned)dloc[q];
            recs[hbase[eb[q]] + rank[q]] = r;
        }
    }
}

// per bucket: count per node, scan, write rowptr + final csr (L2-resident window)
__global__ __launch_bounds__(512)
void bucket_finalize(const uint2* __restrict__ recs, const int* __restrict__ boff,
                     int* __restrict__ rowptr, int* __restrict__ csr,
                     int nN, int nE, int nBuck)
{
    __shared__ int cnt[512];
    __shared__ int sc[512];
    __shared__ int cur[512];
    const int b = blockIdx.x;
    const int t = threadIdx.x;
    const int rbase = boff[b];
    const int rend  = (b + 1 < nBuck) ? boff[b + 1] : nE;
    const int rcnt  = rend - rbase;
    const int node0 = b << 9;
    const int nodes = min(512, nN - node0);
    cnt[t] = 0;
    __syncthreads();
    for (int i = t; i < rcnt; i += 512) atomicAdd(&cnt[recs[rbase + i].y], 1);
    __syncthreads();
    sc[t] = cnt[t];
    __syncthreads();
    for (int off = 1; off < 512; off <<= 1) {
        int v = (t >= off) ? sc[t - off] : 0;
        __syncthreads();
        sc[t] += v;
        __syncthreads();
    }
    int excl = (t == 0) ? 0 : sc[t - 1];
    if (t < nodes) rowptr[node0 + t] = rbase + excl;
    cur[t] = excl;
    __syncthreads();
    for (int i = t; i < rcnt; i += 512) {
        uint2 r = recs[rbase + i];
        int p = atomicAdd(&cur[r.y], 1);
        csr[rbase + p] = (int)r.x;
    }
}

// ================= aggregation (gather) =================
__global__ __launch_bounds__(256)
void agg5_kernel(const float* __restrict__ x, const int* __restrict__ rowptr,
                 const int* __restrict__ csr, float* __restrict__ agg, int nN, int nE)
{
    int n = blockIdx.x * blockDim.x + threadIdx.x;
    if (n >= nN) return;
    int e0 = rowptr[n];
    int e1 = (n + 1 < nN) ? rowptr[n + 1] : nE;
    float a[5] = {0.f, 0.f, 0.f, 0.f, 0.f};
    for (int e = e0; e < e1; ++e) {
        int v = csr[e];
        int s = ((unsigned)v) >> 14;
        float w = (float)(v & 16383) * (1.f / 16383.f);
        const float* xr = x + (size_t)s * 5;
        #pragma unroll
        for (int f = 0; f < 5; ++f) a[f] += w * xr[f];
    }
    float* ar = agg + (size_t)n * 5;
    #pragma unroll
    for (int f = 0; f < 5; ++f) ar[f] = a[f];
}

// bf16 gather: agg[n] = sum_e w_e * h[src_e], 8 cols per thread (ushort8 = 16B)
template<int D>
__global__ __launch_bounds__(256)
void aggD_bf16(const unsigned short* __restrict__ h, const int* __restrict__ rowptr,
               const int* __restrict__ csr, unsigned short* __restrict__ agg,
               int nN, int nE)
{
    constexpr int TPN = D / 8;
    int gid = blockIdx.x * blockDim.x + threadIdx.x;
    int c = gid & (TPN - 1);
    int n = gid / TPN;
    if (n >= nN) return;
    int e0 = rowptr[n];
    int e1 = (n + 1 < nN) ? rowptr[n + 1] : nE;
    float acc[8] = {0.f, 0.f, 0.f, 0.f, 0.f, 0.f, 0.f, 0.f};
    for (int e = e0; e < e1; ++e) {
        int v = csr[e];
        int s = ((unsigned)v) >> 14;
        float w = (float)(v & 16383) * (1.f / 16383.f);
        const ushort8b hv = *(const ushort8b*)(h + (size_t)s * D + c * 8);
        #pragma unroll
        for (int q = 0; q < 8; ++q) acc[q] += w * bf2f(hv[q]);
    }
    ushort8b o;
    #pragma unroll
    for (int q = 0; q < 8; ++q) o[q] = f2bf(acc[q]);
    *(ushort8b*)(agg + (size_t)n * D + c * 8) = o;
}

// -------- small conv (layer 0): out_bf16 = relu(x@ws + agg@wn + b) --------
template<int DIN, int DOUT>
__global__ __launch_bounds__(512)
void conv_mm(const float* __restrict__ h, const float* __restrict__ agg,
             const float* __restrict__ ws, const float* __restrict__ wn,
             const float* __restrict__ bias, unsigned short* __restrict__ out, int nN)
{
    __shared__ __align__(16) float s_w[2 * DIN * DOUT];
    __shared__ __align__(16) float s_b[DOUT];
    for (int i = threadIdx.x; i < DIN * DOUT; i += 512) {
        s_w[i] = ws[i];
        s_w[DIN * DOUT + i] = wn[i];
    }
    for (int i = threadIdx.x; i < DOUT; i += 512) s_b[i] = bias[i];
    __syncthreads();

    constexpr int TPN = DOUT / 4;
    constexpr int HALF = 512 / TPN;
    constexpr int NPASS = HALF * 2;
    const int jj = (threadIdx.x % TPN) * 4;
    const int nsub = threadIdx.x / TPN;

    for (int base = blockIdx.x * NPASS; base < nN; base += gridDim.x * NPASS) {
        int n0 = base + nsub;
        int n1 = base + nsub + HALF;
        bool v0 = n0 < nN, v1 = n1 < nN;
        int n0c = v0 ? n0 : nN - 1;
        int n1c = v1 ? n1 : nN - 1;

        float acc0[4], acc1[4];
        #pragma unroll
        for (int q = 0; q < 4; ++q) { acc0[q] = s_b[jj + q]; acc1[q] = s_b[jj + q]; }

        const float* p0 = h + (size_t)n0c * DIN;
        const float* p1 = h + (size_t)n1c * DIN;
        const float* a0 = agg + (size_t)n0c * DIN;
        const float* a1 = agg + (size_t)n1c * DIN;

        for (int k = 0; k < DIN; ++k) {
            float xs0 = p0[k], xs1 = p1[k];
            const float4 w4 = *(const float4*)(s_w + (size_t)k * DOUT + jj);
            acc0[0] += xs0 * w4.x; acc0[1] += xs0 * w4.y;
            acc0[2] += xs0 * w4.z; acc0[3] += xs0 * w4.w;
            acc1[0] += xs1 * w4.x; acc1[1] += xs1 * w4.y;
            acc1[2] += xs1 * w4.z; acc1[3] += xs1 * w4.w;
        }
        for (int k = 0; k < DIN; ++k) {
            float xs0 = a0[k], xs1 = a1[k];
            const float4 w4 = *(const float4*)(s_w + (size_t)(DIN + k) * DOUT + jj);
            acc0[0] += xs0 * w4.x; acc0[1] += xs0 * w4.y;
            acc0[2] += xs0 * w4.z; acc0[3] += xs0 * w4.w;
            acc1[0] += xs1 * w4.x; acc1[1] += xs1 * w4.y;
            acc1[2] += xs1 * w4.z; acc1[3] += xs1 * w4.w;
        }
        if (v0) {
            ushort4 o;
            o.x = f2bf(fmaxf(acc0[0], 0.f)); o.y = f2bf(fmaxf(acc0[1], 0.f));
            o.z = f2bf(fmaxf(acc0[2], 0.f)); o.w = f2bf(fmaxf(acc0[3], 0.f));
            *(ushort4*)(out + (size_t)n0 * DOUT + jj) = o;
        }
        if (v1) {
            ushort4 o;
            o.x = f2bf(fmaxf(acc1[0], 0.f)); o.y = f2bf(fmaxf(acc1[1], 0.f));
            o.z = f2bf(fmaxf(acc1[2], 0.f)); o.w = f2bf(fmaxf(acc1[3], 0.f));
            *(ushort4*)(out + (size_t)n1 * DOUT + jj) = o;
        }
    }
}

// -------- weight prep: Wt[col][k] bf16, k = [self(DIN) | nei(DIN)] --------
template<int DIN>
__global__ __launch_bounds__(256)
void prep_w(const float* __restrict__ ws, const float* __restrict__ wn,
            unsigned short* __restrict__ wt)
{
    constexpr int KC = 2 * DIN;
    int idx = blockIdx.x * 256 + threadIdx.x;
    if (idx >= 128 * KC) return;
    int col = idx / KC, k = idx % KC;
    float v = (k < DIN) ? ws[(size_t)k * 128 + col] : wn[(size_t)(k - DIN) * 128 + col];
    wt[(size_t)col * KC + k] = f2bf(v);
}

// -------- big conv via MFMA: out = relu([h|agg] @ [ws;wn] + b), bf16 in/out --------
template<int DIN, bool POOL>
__global__ __launch_bounds__(256)
void conv_mfma(const unsigned short* __restrict__ h, const unsigned short* __restrict__ agg,
               const unsigned short* __restrict__ wt,   // [128][2*DIN] bf16
               const float* __restrict__ bias, unsigned short* __restrict__ out,
               const int* __restrict__ bl, float* __restrict__ sums, int nN)
{
    constexpr int KC = 2 * DIN;
    constexpr int NPANEL = KC / 64;
    constexpr int LDK = 72;
    constexpr int SMEM_BYTES = POOL ? 33280 : 27648;
    __shared__ __align__(16) unsigned char smem[SMEM_BYTES];
    unsigned short* sA = (unsigned short*)smem;
    unsigned short* sB = (unsigned short*)(smem + 9216);

    const int tid  = threadIdx.x;
    const int lane = tid & 63;
    const int w    = tid >> 6;
    const int nb   = (w >> 1) * 32;
    const int cb   = (w & 1) * 64;
    const int r15  = lane & 15;
    const int k8   = (lane >> 4) * 8;
    const int tile0 = blockIdx.x * 64;

    const floatx4 zero4 = {0.f, 0.f, 0.f, 0.f};
    floatx4 acc[2][4];
    #pragma unroll
    for (int m = 0; m < 2; ++m)
        #pragma unroll
        for (int n = 0; n < 4; ++n) acc[m][n] = zero4;

    for (int kp = 0; kp < NPANEL; ++kp) {
        const int kbase = kp * 64;
        const unsigned short* M = (kbase < DIN) ? h : agg;
        const int koff = (kbase < DIN) ? kbase : (kbase - DIN);
        #pragma unroll
        for (int r = 0; r < 2; ++r) {
            int f = tid + r * 256;
            int node = f >> 3, kq = f & 7;
            *(ushort8b*)(&sA[node * LDK + kq * 8]) =
                *(const ushort8b*)(M + (size_t)(tile0 + node) * DIN + koff + kq * 8);
        }
        #pragma unroll
        for (int r = 0; r < 4; ++r) {
            int f = tid + r * 256;
            int col = f >> 3, kq = f & 7;
            *(ushort8b*)(&sB[col * LDK + kq * 8]) =
                *(const ushort8b*)(wt + (size_t)col * KC + kbase + kq * 8);
        }
        __syncthreads();
        #pragma unroll
        for (int ks = 0; ks < 2; ++ks) {
            const int kk = ks * 32 + k8;
            short8b a0 = *(const short8b*)(&sA[(nb + r15) * LDK + kk]);
            short8b a1 = *(const short8b*)(&sA[(nb + 16 + r15) * LDK + kk]);
            #pragma unroll
            for (int n = 0; n < 4; ++n) {
                short8b b = *(const short8b*)(&sB[(cb + n * 16 + r15) * LDK + kk]);
                acc[0][n] = __builtin_amdgcn_mfma_f32_16x16x32_bf16(a0, b, acc[0][n], 0, 0, 0);
                acc[1][n] = __builtin_amdgcn_mfma_f32_16x16x32_bf16(a1, b, acc[1][n], 0, 0, 0);
            }
        }
        __syncthreads();
    }

    const int row4 = (lane >> 4) * 4;
    if constexpr (POOL) {
        float* s_out = (float*)smem;          // [64][129]
        int*   s_gl  = (int*)(smem + 33024);  // [64]
        #pragma unroll
        for (int n = 0; n < 4; ++n) {
            const int col = cb + n * 16 + r15;
            const float bv = bias[col];
            #pragma unroll
            for (int m = 0; m < 2; ++m) {
                #pragma unroll
                for (int j = 0; j < 4; ++j) {
                    int row = nb + m * 16 + row4 + j;
                    s_out[row * 129 + col] = fmaxf(acc[m][n][j] + bv, 0.f);
                }
            }
        }
        if (tid < 64) s_gl[tid] = bl[tile0 + tid];
        __syncthreads();
        {
            const int col  = tid & 127;
            const int r0   = (tid >> 7) * 32;
            float run = 0.f;
            int gprev = s_gl[r0];
            for (int r = r0; r < r0 + 32; ++r) {
                int g = s_gl[r];
                float v = s_out[r * 129 + col];
                if (g != gprev) {
                    unsafeAtomicAdd(&sums[(size_t)gprev * 128 + col], run);
                    run = v;
                    gprev = g;
                } else {
                    run += v;
                }
            }
            unsafeAtomicAdd(&sums[(size_t)gprev * 128 + col], run);
        }
    } else {
        #pragma unroll
        for (int n = 0; n < 4; ++n) {
            const int col = cb + n * 16 + r15;
            const float bv = bias[col];
            #pragma unroll
            for (int m = 0; m < 2; ++m) {
                #pragma unroll
                for (int j = 0; j < 4; ++j) {
                    int node = tile0 + nb + m * 16 + row4 + j;
                    out[(size_t)node * 128 + col] = f2bf(fmaxf(acc[m][n][j] + bv, 0.f));
                }
            }
        }
    }
}

// ---------------- per-graph node counts (binary search, no atomics) ----------------
__global__ __launch_bounds__(256)
void cnt_bs(const int* __restrict__ bl, float* __restrict__ cnt, int nN, int nG)
{
    int g = blockIdx.x * blockDim.x + threadIdx.x;
    if (g >= nG) return;
    int lo = 0, hi = nN;
    while (lo < hi) { int mid = (lo + hi) >> 1; if (bl[mid] < g) lo = mid + 1; else hi = mid; }
    int s = lo;
    hi = nN;
    while (lo < hi) { int mid = (lo + hi) >> 1; if (bl[mid] < g + 1) lo = mid + 1; else hi = mid; }
    cnt[g] = (float)(lo - s);
}

// ---------------- GRU (2 layers) + decoder, one block per sequence ----------------
__global__ __launch_bounds__(384)
void gru_kernel(const float* __restrict__ sums, const float* __restrict__ cnt,
                const int* __restrict__ lmap,
                const float* __restrict__ wih0, const float* __restrict__ whh0,
                const float* __restrict__ bih0, const float* __restrict__ bhh0,
                const float* __restrict__ wih1, const float* __restrict__ whh1,
                const float* __restrict__ bih1, const float* __restrict__ bhh1,
                const float* __restrict__ wdec, const float* __restrict__ bdec,
                float* __restrict__ out, int nG)
{
    __shared__ __align__(16) float s_x[16][128];
    __shared__ __align__(16) float s_xp[16][384];
    __shared__ __align__(16) float s_h[128];
    __shared__ __align__(16) float s_gh[384];

    const int b = blockIdx.x;
    const int tid = threadIdx.x;

    for (int i = tid; i < 16 * 128; i += 384) {
        int t = i >> 7, j = i & 127;
        int g = lmap[b * 16 + t];
        s_x[t][j] = sums[(size_t)g * 128 + j] / fmaxf(cnt[g], 1.0f);
    }
    __syncthreads();

    for (int layer = 0; layer < 2; ++layer) {
        const float* wih = layer ? wih1 : wih0;
        const float* whh = layer ? whh1 : whh0;
        const float* bih = layer ? bih1 : bih0;
        const float* bhh = layer ? bhh1 : bhh0;

        {
            const int g = tid;
            float acc[16];
            #pragma unroll
            for (int t = 0; t < 16; ++t) acc[t] = 0.f;
            for (int kc = 0; kc < 32; ++kc) {
                float4 w = *(const float4*)(wih + (size_t)g * 128 + kc * 4);
                #pragma unroll
                for (int t = 0; t < 16; ++t) {
                    float4 xv = *(const float4*)&s_x[t][kc * 4];
                    acc[t] += w.x * xv.x + w.y * xv.y + w.z * xv.z + w.w * xv.w;
                }
            }
            float bg = bih[g];
            #pragma unroll
            for (int t = 0; t < 16; ++t) s_xp[t][g] = acc[t] + bg;
        }
        __syncthreads();
        if (tid < 128) s_h[tid] = 0.f;
        __syncthreads();

        for (int t = 0; t < 16; ++t) {
            {
                const int g = tid;
                float acc = bhh[g];
                for (int kc = 0; kc < 32; ++kc) {
                    float4 w = *(const float4*)(whh + (size_t)g * 128 + kc * 4);
                    float4 hv = *(const float4*)&s_h[kc * 4];
                    acc += w.x * hv.x + w.y * hv.y + w.z * hv.z + w.w * hv.w;
                }
                s_gh[g] = acc;
            }
            __syncthreads();
            if (tid < 128) {
                int j = tid;
                float r = sigm(s_xp[t][j] + s_gh[j]);
                float z = sigm(s_xp[t][128 + j] + s_gh[128 + j]);
                float n = tanhf(s_xp[t][256 + j] + r * s_gh[256 + j]);
                float hn = (1.f - z) * n + z * s_h[j];
                s_h[j] = hn;
                s_x[t][j] = hn;
            }
            __syncthreads();
        }
    }

    if (tid < 16) {
        float acc = bdec[0];
        const float* o = &s_x[tid][0];
        for (int j = 0; j < 128; ++j) acc += o[j] * wdec[j];
        float p = sigm(acc);
        out[b * 16 + tid] = p;
        if (tid == 15) out[nG + b] = p;
    }
}

extern "C" void kernel_launch(void* const* d_in, const int* in_sizes, int n_in,
                              void* d_out, int out_size, void* d_ws, size_t ws_size,
                              hipStream_t stream)
{
    const float* x    = (const float*)d_in[0];
    const float* ea   = (const float*)d_in[1];
    const int*   ei   = (const int*)d_in[2];
    const int*   bl   = (const int*)d_in[3];
    const int*   lmap = (const int*)d_in[4];
    const float* ws0 = (const float*)d_in[5];
    const float* wn0 = (const float*)d_in[6];
    const float* b0  = (const float*)d_in[7];
    const float* ws1 = (const float*)d_in[8];
    const float* wn1 = (const float*)d_in[9];
    const float* b1  = (const float*)d_in[10];
    const float* ws2 = (const float*)d_in[11];
    const float* wn2 = (const float*)d_in[12];
    const float* b2  = (const float*)d_in[13];
    const float* wih0 = (const float*)d_in[14];
    const float* whh0 = (const float*)d_in[15];
    const float* bih0 = (const float*)d_in[16];
    const float* bhh0 = (const float*)d_in[17];
    const float* wih1 = (const float*)d_in[18];
    const float* whh1 = (const float*)d_in[19];
    const float* bih1 = (const float*)d_in[20];
    const float* bhh1 = (const float*)d_in[21];
    const float* wdec = (const float*)d_in[22];
    const float* bdec = (const float*)d_in[23];
    float* out = (float*)d_out;

    const int nN = in_sizes[0] / 5;     // 200000
    const int nE = in_sizes[1];         // 1600000
    const int nG = in_sizes[4];         // 4096
    const int B  = nG / 16;             // 256
    const int nBuck = (nN + 511) >> 9;  // 391

    const int* src = ei;
    const int* dst = ei + nE;

    // Workspace (~129 MB)
    unsigned short* R0   = (unsigned short*)d_ws;      // nN*64 bf16: h1, later agg128 lo
    unsigned short* R1   = R0 + (size_t)nN * 64;       // nN*64 bf16: agg64, later agg128 hi
    unsigned short* R2   = R1 + (size_t)nN * 64;       // nN*128 bf16: h2
    unsigned short* agg128b = R0;                      // alias R0∪R1
    float* agg5 = (float*)(R2 + (size_t)nN * 128);     // nN*5 f32
    float* sums = agg5 + (size_t)nN * 5;               // nG*128 f32
    float* cnt  = sums + (size_t)nG * 128;
    int* rowptr = (int*)(cnt + nG);                    // nN
    int* bcnt   = rowptr + nN;                         // 512
    int* boff   = bcnt + 512;                          // 512
    int* bcur   = boff + 512;                          // 512
    uint2* recs = (uint2*)(bcur + 512);                // nE uint2 (8B-aligned by layout)
    int* csr    = (int*)(recs + nE);                   // nE
    unsigned short* wt1 = (unsigned short*)(csr + nE); // [128][128] bf16
    unsigned short* wt2 = wt1 + 128 * 128;             // [128][256] bf16

    // ---- build CSR via two-level binned counting sort ----
    hipMemsetAsync(bcnt, 0, 512 * sizeof(int), stream);
    bucket_hist<<<256, 512, 0, stream>>>(dst, bcnt, nE, nBuck);
    scan_blocks<<<1, 256, 0, stream>>>(bcnt, boff, nullptr, nBuck);
    hipMemcpyAsync(bcur, boff, nBuck * sizeof(int), hipMemcpyDeviceToDevice, stream);
    bucket_scatter<<<(nE + 8191) / 8192, 512, 0, stream>>>(src, dst, ea, bcur, recs, nE);
    bucket_finalize<<<nBuck, 512, 0, stream>>>(recs, boff, rowptr, csr, nN, nE, nBuck);

    // ---- weight prep (transpose + bf16) ----
    prep_w<64><<<(128 * 128 + 255) / 256, 256, 0, stream>>>(ws1, wn1, wt1);
    prep_w<128><<<(128 * 256 + 255) / 256, 256, 0, stream>>>(ws2, wn2, wt2);

    // ---- layer 0: agg x (5) -> agg5; h1 = conv(x, agg5) -> R0 (bf16) ----
    agg5_kernel<<<(nN + 255) / 256, 256, 0, stream>>>(x, rowptr, csr, agg5, nN, nE);
    conv_mm<5, 64><<<512, 512, 0, stream>>>(x, agg5, ws0, wn0, b0, R0, nN);

    // ---- layer 1: agg h1 (bf16) -> R1; h2 = conv_mfma -> R2 (bf16) ----
    aggD_bf16<64><<<(nN * 8 + 255) / 256, 256, 0, stream>>>(R0, rowptr, csr, R1, nN, nE);
    conv_mfma<64, false><<<nN / 64, 256, 0, stream>>>(R0, R1, wt1, b1, R2, nullptr, nullptr, nN);

    // ---- layer 2: agg h2 (bf16) -> agg128b; conv_mfma with fused pooled sums ----
    aggD_bf16<128><<<(nN * 16 + 255) / 256, 256, 0, stream>>>(R2, rowptr, csr, agg128b, nN, nE);
    hipMemsetAsync(sums, 0, (size_t)nG * 128 * sizeof(float), stream);
    cnt_bs<<<(nG + 255) / 256, 256, 0, stream>>>(bl, cnt, nN, nG);
    conv_mfma<128, true><<<nN / 64, 256, 0, stream>>>(R2, agg128b, wt2, b2, nullptr, bl, sums, nN);

    // ---- GRU x2 + decoder ----
    gru_kernel<<<B, 384, 0, stream>>>(sums, cnt, lmap,
                                      wih0, whh0, bih0, bhh0,
                                      wih1, whh1, bih1, bhh1,
                                      wdec, bdec, out, nG);
}